// Round 1
// baseline (1190.379 us; speedup 1.0000x reference)
//
#include <hip/hip_runtime.h>
#include <math.h>

typedef short short8 __attribute__((ext_vector_type(8)));
typedef float f32x4 __attribute__((ext_vector_type(4)));
typedef unsigned short u16;
typedef u16 us4 __attribute__((ext_vector_type(4)));

#define DEVI static __device__ __forceinline__

constexpr float SCALE_Q = 0.17677669529663687f;  // 32^-0.5

DEVI u16 f2bf(float f) {
  unsigned u = __builtin_bit_cast(unsigned, f);
  u += 0x7FFFu + ((u >> 16) & 1u);
  return (u16)(u >> 16);
}

// ---------------- weight fp32 -> bf16 ----------------
__global__ void cvt_bf16(const float4* __restrict__ src, us4* __restrict__ dst, int n4) {
  int i = blockIdx.x * 256 + threadIdx.x;
  if (i < n4) {
    float4 v = src[i];
    us4 o = { f2bf(v.x), f2bf(v.y), f2bf(v.z), f2bf(v.w) };
    dst[i] = o;
  }
}

// ---------------- LayerNorm (+ optional roll + dilated window partition) ----------------
// PERM: out token m = ((b*64 + i2*8 + j2)*64 + s1*8 + s2); reads x[b, (s1*8+i2+4)&63, (s2*8+j2+4)&63]
template<bool PERM>
__global__ __launch_bounds__(256) void ln_kernel(const float* __restrict__ src,
                                                 const float* __restrict__ gw,
                                                 const float* __restrict__ gb,
                                                 u16* __restrict__ dst) {
  int wid = threadIdx.x >> 6, lane = threadIdx.x & 63;
  int m = blockIdx.x * 4 + wid;
  int srow;
  if (PERM) {
    int b = m >> 12;
    int win = (m >> 6) & 63, t = m & 63;
    int i2 = win >> 3, j2 = win & 7, s1 = t >> 3, s2 = t & 7;
    int h = (s1 * 8 + i2 + 4) & 63, w = (s2 * 8 + j2 + 4) & 63;
    srow = (b << 12) + h * 64 + w;
  } else {
    srow = m;
  }
  const float4* r4 = (const float4*)(src + (size_t)srow * 512);
  float4 v0 = r4[lane], v1 = r4[lane + 64];
  float s  = v0.x + v0.y + v0.z + v0.w + v1.x + v1.y + v1.z + v1.w;
  float ss = v0.x*v0.x + v0.y*v0.y + v0.z*v0.z + v0.w*v0.w
           + v1.x*v1.x + v1.y*v1.y + v1.z*v1.z + v1.w*v1.w;
  #pragma unroll
  for (int off = 1; off < 64; off <<= 1) {
    s  += __shfl_xor(s, off);
    ss += __shfl_xor(ss, off);
  }
  float mean = s * (1.f/512.f);
  float var  = ss * (1.f/512.f) - mean*mean;
  float rstd = rsqrtf(var + 1e-5f);
  const float4* w4 = (const float4*)gw;
  const float4* b4 = (const float4*)gb;
  float4 wa = w4[lane], ba = b4[lane], wb = w4[lane+64], bb = b4[lane+64];
  us4 o0 = { f2bf((v0.x-mean)*rstd*wa.x + ba.x),
             f2bf((v0.y-mean)*rstd*wa.y + ba.y),
             f2bf((v0.z-mean)*rstd*wa.z + ba.z),
             f2bf((v0.w-mean)*rstd*wa.w + ba.w) };
  us4 o1 = { f2bf((v1.x-mean)*rstd*wb.x + bb.x),
             f2bf((v1.y-mean)*rstd*wb.y + bb.y),
             f2bf((v1.z-mean)*rstd*wb.z + bb.z),
             f2bf((v1.w-mean)*rstd*wb.w + bb.w) };
  us4* d4 = (us4*)(dst + (size_t)m * 512);
  d4[lane] = o0; d4[lane + 64] = o1;
}

// ---------------- GEMM: C[M,N] = A[M,K](bf16) @ W[N,K]^T(bf16) + bias, fused epilogues ----
// MODE 0: qkv scatter -> q(scaled), k: (w,head,t,d); v: transposed (w,head,d,t)
// MODE 1: proj: fo[win_reverse(row), col] = resid[same] + val
// MODE 2: fc1: gelu(val) -> o0 bf16 (ldc = N)
// MODE 3: fc2: fo[row*512+col] += val (in-place residual)
template<int MODE>
__global__ __launch_bounds__(256) void gemm_k(const u16* __restrict__ A,
                                              const u16* __restrict__ Bw,
                                              const float* __restrict__ bias,
                                              u16* __restrict__ o0, u16* __restrict__ o1,
                                              u16* __restrict__ o2,
                                              float* __restrict__ fo,
                                              const float* __restrict__ resid,
                                              int M, int N, int K) {
  __shared__ u16 As[128][32];
  __shared__ u16 Bs[128][32];
  int nt = N >> 7;
  int tm = blockIdx.x / nt, tn = blockIdx.x % nt;
  int tid = threadIdx.x;
  int lane = tid & 63, wv = tid >> 6;
  int wm = wv >> 1, wn = wv & 1;

  int rA = tid >> 2;
  int c8 = (tid & 3) << 3;
  const u16* ag = A  + (size_t)(tm * 128 + rA) * K + c8;
  const u16* bg = Bw + (size_t)(tn * 128 + rA) * K + c8;
  size_t k64 = (size_t)64 * K;

  f32x4 acc[4][4] = {};
  int rr = lane & 15, g8 = (lane >> 4) << 3;

  for (int k0 = 0; k0 < K; k0 += 32) {
    *(short8*)(&As[rA][c8])      = *(const short8*)(ag);
    *(short8*)(&As[rA + 64][c8]) = *(const short8*)(ag + k64);
    *(short8*)(&Bs[rA][c8])      = *(const short8*)(bg);
    *(short8*)(&Bs[rA + 64][c8]) = *(const short8*)(bg + k64);
    ag += 32; bg += 32;
    __syncthreads();
    short8 af[4], bf[4];
    #pragma unroll
    for (int i = 0; i < 4; i++) af[i] = *(const short8*)(&As[wm*64 + i*16 + rr][g8]);
    #pragma unroll
    for (int i = 0; i < 4; i++) bf[i] = *(const short8*)(&Bs[wn*64 + i*16 + rr][g8]);
    #pragma unroll
    for (int mi = 0; mi < 4; mi++)
      #pragma unroll
      for (int ni = 0; ni < 4; ni++)
        acc[mi][ni] = __builtin_amdgcn_mfma_f32_16x16x32_bf16(af[mi], bf[ni], acc[mi][ni], 0, 0, 0);
    __syncthreads();
  }

  int rb = tm*128 + wm*64 + ((lane >> 4) << 2);
  int cb = tn*128 + wn*64 + rr;
  #pragma unroll
  for (int ni = 0; ni < 4; ni++) {
    int col = cb + ni*16;
    float bv = bias[col];
    int head = 0, d = 0, which = 0;
    if (MODE == 0) { head = col / 96; int rem = col - head*96; d = rem / 3; which = rem - d*3; }
    #pragma unroll
    for (int mi = 0; mi < 4; mi++) {
      #pragma unroll
      for (int r = 0; r < 4; r++) {
        int row = rb + mi*16 + r;
        float val = acc[mi][ni][r] + bv;
        if (MODE == 0) {
          int w = row >> 6, t = row & 63;
          if (which == 0)      o0[((size_t)(w*16 + head)*64 + t)*32 + d] = f2bf(val * SCALE_Q);
          else if (which == 1) o1[((size_t)(w*16 + head)*64 + t)*32 + d] = f2bf(val);
          else                 o2[((size_t)(w*16 + head)*32 + d)*64 + t] = f2bf(val);
        } else if (MODE == 1) {
          int w = row >> 6, t = row & 63;
          int b = w >> 6, win = w & 63;
          int i2 = win >> 3, j2 = win & 7, s1 = t >> 3, s2 = t & 7;
          int pos = (b << 12) + (s1*8 + i2)*64 + (s2*8 + j2);
          size_t idx = (size_t)pos * 512 + col;
          fo[idx] = resid[idx] + val;
        } else if (MODE == 2) {
          float gl = 0.5f * val * (1.f + erff(val * 0.70710678118654752f));
          o0[(size_t)row * N + col] = f2bf(gl);
        } else {
          size_t idx = (size_t)row * 512 + col;
          fo[idx] += val;
        }
      }
    }
  }
}

// ---------------- attention: one wave per (window, head) ----------------
DEVI int zone1(int x) { return x < 56 ? 0 : (x < 60 ? 1 : 2); }

__global__ __launch_bounds__(256) void attn_k(const u16* __restrict__ qb,
                                              const u16* __restrict__ kb,
                                              const u16* __restrict__ vtb,
                                              const float* __restrict__ rpb,
                                              u16* __restrict__ outb) {
  __shared__ u16 P[4][64][72];  // +8 pad breaks 128B-stride bank conflicts on A-frag reads
  int wid = threadIdx.x >> 6, lane = threadIdx.x & 63;
  int p = blockIdx.x * 4 + wid;          // (window, head) pair id
  int w = p >> 4, head = p & 15;
  const u16* qq = qb  + (size_t)p * 2048;
  const u16* kk = kb  + (size_t)p * 2048;
  const u16* vv = vtb + (size_t)p * 2048;
  int rr = lane & 15, g = lane >> 4;

  short8 qf[4], kf[4];
  #pragma unroll
  for (int i = 0; i < 4; i++) qf[i] = *(const short8*)(qq + (i*16 + rr)*32 + g*8);
  #pragma unroll
  for (int i = 0; i < 4; i++) kf[i] = *(const short8*)(kk + (i*16 + rr)*32 + g*8);

  f32x4 zero = {0.f, 0.f, 0.f, 0.f};
  f32x4 s[4][4];
  #pragma unroll
  for (int qi = 0; qi < 4; qi++)
    #pragma unroll
    for (int kj = 0; kj < 4; kj++)
      s[qi][kj] = __builtin_amdgcn_mfma_f32_16x16x32_bf16(qf[qi], kf[kj], zero, 0, 0, 0);

  // relative-position bias + shift mask (procedural)
  int win = w & 63, i2 = win >> 3, j2 = win & 7;
  #pragma unroll
  for (int qi = 0; qi < 4; qi++) {
    #pragma unroll
    for (int r = 0; r < 4; r++) {
      int i = qi*16 + g*4 + r;
      int s1i = i >> 3, s2i = i & 7;
      int zi = zone1(s1i*8 + i2)*3 + zone1(s2i*8 + j2);
      #pragma unroll
      for (int kj = 0; kj < 4; kj++) {
        int j = kj*16 + rr;
        int s1j = j >> 3, s2j = j & 7;
        float bv = rpb[((s1i - s1j + 7)*15 + (s2i - s2j + 7))*16 + head];
        int zj = zone1(s1j*8 + i2)*3 + zone1(s2j*8 + j2);
        s[qi][kj][r] += bv + (zi != zj ? -1e10f : 0.f);
      }
    }
  }

  // row softmax (rows live on 16-lane groups; cols = lane&15 across 4 kj frags)
  float inv[4][4];
  #pragma unroll
  for (int qi = 0; qi < 4; qi++) {
    #pragma unroll
    for (int r = 0; r < 4; r++) {
      float mx = fmaxf(fmaxf(s[qi][0][r], s[qi][1][r]), fmaxf(s[qi][2][r], s[qi][3][r]));
      mx = fmaxf(mx, __shfl_xor(mx, 1));
      mx = fmaxf(mx, __shfl_xor(mx, 2));
      mx = fmaxf(mx, __shfl_xor(mx, 4));
      mx = fmaxf(mx, __shfl_xor(mx, 8));
      float sum = 0.f;
      #pragma unroll
      for (int kj = 0; kj < 4; kj++) {
        float e = __expf(s[qi][kj][r] - mx);
        s[qi][kj][r] = e;
        sum += e;
      }
      sum += __shfl_xor(sum, 1);
      sum += __shfl_xor(sum, 2);
      sum += __shfl_xor(sum, 4);
      sum += __shfl_xor(sum, 8);
      inv[qi][r] = 1.f / sum;
    }
  }

  // P (D-layout) -> LDS -> A-frags
  #pragma unroll
  for (int qi = 0; qi < 4; qi++)
    #pragma unroll
    for (int kj = 0; kj < 4; kj++)
      #pragma unroll
      for (int r = 0; r < 4; r++)
        P[wid][qi*16 + g*4 + r][kj*16 + rr] = f2bf(s[qi][kj][r]);

  f32x4 o[4][2] = {};
  #pragma unroll
  for (int jh = 0; jh < 2; jh++) {
    short8 vf[2];
    #pragma unroll
    for (int df = 0; df < 2; df++)
      vf[df] = *(const short8*)(vv + (size_t)(df*16 + rr)*64 + jh*32 + g*8);
    #pragma unroll
    for (int qi = 0; qi < 4; qi++) {
      short8 pf = *(const short8*)(&P[wid][qi*16 + rr][jh*32 + g*8]);
      #pragma unroll
      for (int df = 0; df < 2; df++)
        o[qi][df] = __builtin_amdgcn_mfma_f32_16x16x32_bf16(pf, vf[df], o[qi][df], 0, 0, 0);
    }
  }

  #pragma unroll
  for (int qi = 0; qi < 4; qi++)
    #pragma unroll
    for (int df = 0; df < 2; df++)
      #pragma unroll
      for (int r = 0; r < 4; r++) {
        int t = qi*16 + g*4 + r;
        int d = df*16 + rr;
        outb[(size_t)(w*64 + t)*512 + head*32 + d] = f2bf(o[qi][df][r] * inv[qi][r]);
      }
}

extern "C" void kernel_launch(void* const* d_in, const int* in_sizes, int n_in,
                              void* d_out, int out_size, void* d_ws, size_t ws_size,
                              hipStream_t stream) {
  const float* x     = (const float*)d_in[0];
  const float* ln1w  = (const float*)d_in[1];
  const float* ln1b  = (const float*)d_in[2];
  const float* qkvw  = (const float*)d_in[3];
  const float* qkvb  = (const float*)d_in[4];
  const float* rpb   = (const float*)d_in[5];
  const float* projw = (const float*)d_in[6];
  const float* projb = (const float*)d_in[7];
  const float* ln2w  = (const float*)d_in[8];
  const float* ln2b  = (const float*)d_in[9];
  const float* fc1w  = (const float*)d_in[10];
  const float* fc1b  = (const float*)d_in[11];
  const float* fc2w  = (const float*)d_in[12];
  const float* fc2b  = (const float*)d_in[13];
  float* out = (float*)d_out;

  char* ws = (char*)d_ws;
  u16* wqkv  = (u16*)(ws + 0);         // 786432 el
  u16* wproj = (u16*)(ws + 1572864);   // 262144 el
  u16* wfc1  = (u16*)(ws + 2097152);   // 1048576 el
  u16* wfc2  = (u16*)(ws + 4194304);   // 1048576 el
  size_t base = 8ull << 20;
  u16* xw = (u16*)(ws + base);                      // 64 MiB  (aliased later: attn, z)
  u16* qb = (u16*)(ws + base + (64ull  << 20));     // 64 MiB  (aliased later: part of h)
  u16* kb = (u16*)(ws + base + (128ull << 20));     // 64 MiB
  u16* vb = (u16*)(ws + base + (192ull << 20));     // 64 MiB
  u16* attnb = xw;
  u16* zb    = xw;
  u16* hb    = qb;                                  // 256 MiB -> ws end 328 MiB

  // weights -> bf16
  cvt_bf16<<<768,  256, 0, stream>>>((const float4*)qkvw,  (us4*)wqkv,  196608);
  cvt_bf16<<<256,  256, 0, stream>>>((const float4*)projw, (us4*)wproj, 65536);
  cvt_bf16<<<1024, 256, 0, stream>>>((const float4*)fc1w,  (us4*)wfc1,  262144);
  cvt_bf16<<<1024, 256, 0, stream>>>((const float4*)fc2w,  (us4*)wfc2,  262144);

  // LN1 + roll + window partition
  ln_kernel<true><<<16384, 256, 0, stream>>>(x, ln1w, ln1b, xw);
  // QKV
  gemm_k<0><<<512*12, 256, 0, stream>>>(xw, wqkv, qkvb, qb, kb, vb, nullptr, nullptr,
                                        65536, 1536, 512);
  // attention
  attn_k<<<4096, 256, 0, stream>>>(qb, kb, vb, rpb, attnb);
  // proj + win_reverse + residual -> d_out (= x2)
  gemm_k<1><<<512*4, 256, 0, stream>>>(attnb, wproj, projb, nullptr, nullptr, nullptr,
                                       out, x, 65536, 512, 512);
  // LN2
  ln_kernel<false><<<16384, 256, 0, stream>>>(out, ln2w, ln2b, zb);
  // fc1 + gelu
  gemm_k<2><<<512*16, 256, 0, stream>>>(zb, wfc1, fc1b, hb, nullptr, nullptr, nullptr, nullptr,
                                        65536, 2048, 512);
  // fc2 + residual (in-place on d_out)
  gemm_k<3><<<512*4, 256, 0, stream>>>(hb, wfc2, fc2b, nullptr, nullptr, nullptr, out, nullptr,
                                       65536, 512, 2048);
}

// Round 2
// 1163.706 us; speedup vs baseline: 1.0229x; 1.0229x over previous
//
#include <hip/hip_runtime.h>
#include <math.h>

typedef short short8 __attribute__((ext_vector_type(8)));
typedef float f32x4 __attribute__((ext_vector_type(4)));
typedef unsigned short u16;
typedef u16 us4 __attribute__((ext_vector_type(4)));

#define DEVI static __device__ __forceinline__

constexpr float SCALE_Q = 0.17677669529663687f;  // 32^-0.5

DEVI u16 f2bf(float f) {
  unsigned u = __builtin_bit_cast(unsigned, f);
  u += 0x7FFFu + ((u >> 16) & 1u);
  return (u16)(u >> 16);
}

// async global->LDS, 16B per lane; lds dest = wave-uniform base + lane*16
DEVI void gload16(const u16* g, u16* l) {
  __builtin_amdgcn_global_load_lds((const __attribute__((address_space(1))) void*)g,
                                   (__attribute__((address_space(3))) void*)l,
                                   16, 0, 0);
}

// ---------------- weight fp32 -> bf16 ----------------
__global__ void cvt_bf16(const float4* __restrict__ src, us4* __restrict__ dst, int n4) {
  int i = blockIdx.x * 256 + threadIdx.x;
  if (i < n4) {
    float4 v = src[i];
    us4 o = { f2bf(v.x), f2bf(v.y), f2bf(v.z), f2bf(v.w) };
    dst[i] = o;
  }
}

// ---------------- LayerNorm (+ optional roll + dilated window partition) ----------------
// PERM: out token m = ((b*64 + i2*8 + j2)*64 + s1*8 + s2); reads x[b, (s1*8+i2+4)&63, (s2*8+j2+4)&63]
template<bool PERM>
__global__ __launch_bounds__(256) void ln_kernel(const float* __restrict__ src,
                                                 const float* __restrict__ gw,
                                                 const float* __restrict__ gb,
                                                 u16* __restrict__ dst) {
  int wid = threadIdx.x >> 6, lane = threadIdx.x & 63;
  int m = blockIdx.x * 4 + wid;
  int srow;
  if (PERM) {
    int b = m >> 12;
    int win = (m >> 6) & 63, t = m & 63;
    int i2 = win >> 3, j2 = win & 7, s1 = t >> 3, s2 = t & 7;
    int h = (s1 * 8 + i2 + 4) & 63, w = (s2 * 8 + j2 + 4) & 63;
    srow = (b << 12) + h * 64 + w;
  } else {
    srow = m;
  }
  const float4* r4 = (const float4*)(src + (size_t)srow * 512);
  float4 v0 = r4[lane], v1 = r4[lane + 64];
  float s  = v0.x + v0.y + v0.z + v0.w + v1.x + v1.y + v1.z + v1.w;
  float ss = v0.x*v0.x + v0.y*v0.y + v0.z*v0.z + v0.w*v0.w
           + v1.x*v1.x + v1.y*v1.y + v1.z*v1.z + v1.w*v1.w;
  #pragma unroll
  for (int off = 1; off < 64; off <<= 1) {
    s  += __shfl_xor(s, off);
    ss += __shfl_xor(ss, off);
  }
  float mean = s * (1.f/512.f);
  float var  = ss * (1.f/512.f) - mean*mean;
  float rstd = rsqrtf(var + 1e-5f);
  const float4* w4 = (const float4*)gw;
  const float4* b4 = (const float4*)gb;
  float4 wa = w4[lane], ba = b4[lane], wb = w4[lane+64], bb = b4[lane+64];
  us4 o0 = { f2bf((v0.x-mean)*rstd*wa.x + ba.x),
             f2bf((v0.y-mean)*rstd*wa.y + ba.y),
             f2bf((v0.z-mean)*rstd*wa.z + ba.z),
             f2bf((v0.w-mean)*rstd*wa.w + ba.w) };
  us4 o1 = { f2bf((v1.x-mean)*rstd*wb.x + bb.x),
             f2bf((v1.y-mean)*rstd*wb.y + bb.y),
             f2bf((v1.z-mean)*rstd*wb.z + bb.z),
             f2bf((v1.w-mean)*rstd*wb.w + bb.w) };
  us4* d4 = (us4*)(dst + (size_t)m * 512);
  d4[lane] = o0; d4[lane + 64] = o1;
}

// ---------------- GEMM: C[M,N] = A[M,K](bf16) @ W[N,K]^T(bf16) + bias, fused epilogues ----
// m97 structure: 128x128 tile, BK=32, global_load_lds width-16 staging, XCD swizzle.
// MODE 0: qkv scatter -> q(scaled), k: (w,head,t,d); v: transposed (w,head,d,t)
// MODE 1: proj: fo[win_reverse(row), col] = resid[same] + val
// MODE 2: fc1: gelu(val) -> o0 bf16 (ldc = N)
// MODE 3: fc2: fo[row*512+col] += val (in-place residual)
template<int MODE>
__global__ __launch_bounds__(256) void gemm_k(const u16* __restrict__ A,
                                              const u16* __restrict__ Bw,
                                              const float* __restrict__ bias,
                                              u16* __restrict__ o0, u16* __restrict__ o1,
                                              u16* __restrict__ o2,
                                              float* __restrict__ fo,
                                              const float* __restrict__ resid,
                                              int M, int N, int K) {
  __shared__ u16 As[128][32];
  __shared__ u16 Bs[128][32];
  int nt = N >> 7;
  // XCD-bijective swizzle (grids are multiples of 8): XCD x owns contiguous chunk
  int nwg = gridDim.x;
  int cpx = nwg >> 3;
  int bid = blockIdx.x;
  int swz = (bid & 7) * cpx + (bid >> 3);
  int tm = swz / nt, tn = swz % nt;
  int tid = threadIdx.x;
  int lane = tid & 63, wv = tid >> 6;
  int wm = wv >> 1, wn = wv & 1;

  int rA = tid >> 2;
  int c8 = (tid & 3) << 3;
  const u16* ag = A  + (size_t)(tm * 128 + rA) * K + c8;
  const u16* bg = Bw + (size_t)(tn * 128 + rA) * K + c8;
  size_t k64 = (size_t)64 * K;

  // wave-uniform LDS bases (u16 units): wave wv stages bytes [wv*1024, wv*1024+1024)
  u16* asb = &As[0][0] + wv * 512;
  u16* bsb = &Bs[0][0] + wv * 512;

  f32x4 acc[4][4] = {};
  int rr = lane & 15, g8 = (lane >> 4) << 3;

  for (int k0 = 0; k0 < K; k0 += 32) {
    gload16(ag,       asb);
    gload16(ag + k64, asb + 2048);   // +4096 bytes = rows 64..127
    gload16(bg,       bsb);
    gload16(bg + k64, bsb + 2048);
    ag += 32; bg += 32;
    __syncthreads();
    short8 af[4], bf[4];
    #pragma unroll
    for (int i = 0; i < 4; i++) af[i] = *(const short8*)(&As[wm*64 + i*16 + rr][g8]);
    #pragma unroll
    for (int i = 0; i < 4; i++) bf[i] = *(const short8*)(&Bs[wn*64 + i*16 + rr][g8]);
    #pragma unroll
    for (int mi = 0; mi < 4; mi++)
      #pragma unroll
      for (int ni = 0; ni < 4; ni++)
        acc[mi][ni] = __builtin_amdgcn_mfma_f32_16x16x32_bf16(af[mi], bf[ni], acc[mi][ni], 0, 0, 0);
    __syncthreads();
  }

  int rb = tm*128 + wm*64 + ((lane >> 4) << 2);
  int cb = tn*128 + wn*64 + rr;
  #pragma unroll
  for (int ni = 0; ni < 4; ni++) {
    int col = cb + ni*16;
    float bv = bias[col];
    int head = 0, d = 0, which = 0;
    if (MODE == 0) { head = col / 96; int rem = col - head*96; d = rem / 3; which = rem - d*3; }
    #pragma unroll
    for (int mi = 0; mi < 4; mi++) {
      #pragma unroll
      for (int r = 0; r < 4; r++) {
        int row = rb + mi*16 + r;
        float val = acc[mi][ni][r] + bv;
        if (MODE == 0) {
          int w = row >> 6, t = row & 63;
          if (which == 0)      o0[((size_t)(w*16 + head)*64 + t)*32 + d] = f2bf(val * SCALE_Q);
          else if (which == 1) o1[((size_t)(w*16 + head)*64 + t)*32 + d] = f2bf(val);
          else                 o2[((size_t)(w*16 + head)*32 + d)*64 + t] = f2bf(val);
        } else if (MODE == 1) {
          int w = row >> 6, t = row & 63;
          int b = w >> 6, win = w & 63;
          int i2 = win >> 3, j2 = win & 7, s1 = t >> 3, s2 = t & 7;
          int pos = (b << 12) + (s1*8 + i2)*64 + (s2*8 + j2);
          size_t idx = (size_t)pos * 512 + col;
          fo[idx] = resid[idx] + val;
        } else if (MODE == 2) {
          float gl = 0.5f * val * (1.f + erff(val * 0.70710678118654752f));
          o0[(size_t)row * N + col] = f2bf(gl);
        } else {
          size_t idx = (size_t)row * 512 + col;
          fo[idx] += val;
        }
      }
    }
  }
}

// ---------------- attention: one wave per (window, head) ----------------
DEVI int zone1(int x) { return x < 56 ? 0 : (x < 60 ? 1 : 2); }

__global__ __launch_bounds__(256) void attn_k(const u16* __restrict__ qb,
                                              const u16* __restrict__ kb,
                                              const u16* __restrict__ vtb,
                                              const float* __restrict__ rpb,
                                              u16* __restrict__ outb) {
  __shared__ u16 P[4][64][72];  // +8 pad breaks 128B-stride bank conflicts on A-frag reads
  int wid = threadIdx.x >> 6, lane = threadIdx.x & 63;
  int p = blockIdx.x * 4 + wid;          // (window, head) pair id
  int w = p >> 4, head = p & 15;
  const u16* qq = qb  + (size_t)p * 2048;
  const u16* kk = kb  + (size_t)p * 2048;
  const u16* vv = vtb + (size_t)p * 2048;
  int rr = lane & 15, g = lane >> 4;

  short8 qf[4], kf[4];
  #pragma unroll
  for (int i = 0; i < 4; i++) qf[i] = *(const short8*)(qq + (i*16 + rr)*32 + g*8);
  #pragma unroll
  for (int i = 0; i < 4; i++) kf[i] = *(const short8*)(kk + (i*16 + rr)*32 + g*8);

  f32x4 zero = {0.f, 0.f, 0.f, 0.f};
  f32x4 s[4][4];
  #pragma unroll
  for (int qi = 0; qi < 4; qi++)
    #pragma unroll
    for (int kj = 0; kj < 4; kj++)
      s[qi][kj] = __builtin_amdgcn_mfma_f32_16x16x32_bf16(qf[qi], kf[kj], zero, 0, 0, 0);

  // relative-position bias + shift mask (procedural)
  int win = w & 63, i2 = win >> 3, j2 = win & 7;
  #pragma unroll
  for (int qi = 0; qi < 4; qi++) {
    #pragma unroll
    for (int r = 0; r < 4; r++) {
      int i = qi*16 + g*4 + r;
      int s1i = i >> 3, s2i = i & 7;
      int zi = zone1(s1i*8 + i2)*3 + zone1(s2i*8 + j2);
      #pragma unroll
      for (int kj = 0; kj < 4; kj++) {
        int j = kj*16 + rr;
        int s1j = j >> 3, s2j = j & 7;
        float bv = rpb[((s1i - s1j + 7)*15 + (s2i - s2j + 7))*16 + head];
        int zj = zone1(s1j*8 + i2)*3 + zone1(s2j*8 + j2);
        s[qi][kj][r] += bv + (zi != zj ? -1e10f : 0.f);
      }
    }
  }

  // row softmax (rows live on 16-lane groups; cols = lane&15 across 4 kj frags)
  float inv[4][4];
  #pragma unroll
  for (int qi = 0; qi < 4; qi++) {
    #pragma unroll
    for (int r = 0; r < 4; r++) {
      float mx = fmaxf(fmaxf(s[qi][0][r], s[qi][1][r]), fmaxf(s[qi][2][r], s[qi][3][r]));
      mx = fmaxf(mx, __shfl_xor(mx, 1));
      mx = fmaxf(mx, __shfl_xor(mx, 2));
      mx = fmaxf(mx, __shfl_xor(mx, 4));
      mx = fmaxf(mx, __shfl_xor(mx, 8));
      float sum = 0.f;
      #pragma unroll
      for (int kj = 0; kj < 4; kj++) {
        float e = __expf(s[qi][kj][r] - mx);
        s[qi][kj][r] = e;
        sum += e;
      }
      sum += __shfl_xor(sum, 1);
      sum += __shfl_xor(sum, 2);
      sum += __shfl_xor(sum, 4);
      sum += __shfl_xor(sum, 8);
      inv[qi][r] = 1.f / sum;
    }
  }

  // P (D-layout) -> LDS -> A-frags
  #pragma unroll
  for (int qi = 0; qi < 4; qi++)
    #pragma unroll
    for (int kj = 0; kj < 4; kj++)
      #pragma unroll
      for (int r = 0; r < 4; r++)
        P[wid][qi*16 + g*4 + r][kj*16 + rr] = f2bf(s[qi][kj][r]);

  f32x4 o[4][2] = {};
  #pragma unroll
  for (int jh = 0; jh < 2; jh++) {
    short8 vf[2];
    #pragma unroll
    for (int df = 0; df < 2; df++)
      vf[df] = *(const short8*)(vv + (size_t)(df*16 + rr)*64 + jh*32 + g*8);
    #pragma unroll
    for (int qi = 0; qi < 4; qi++) {
      short8 pf = *(const short8*)(&P[wid][qi*16 + rr][jh*32 + g*8]);
      #pragma unroll
      for (int df = 0; df < 2; df++)
        o[qi][df] = __builtin_amdgcn_mfma_f32_16x16x32_bf16(pf, vf[df], o[qi][df], 0, 0, 0);
    }
  }

  #pragma unroll
  for (int qi = 0; qi < 4; qi++)
    #pragma unroll
    for (int df = 0; df < 2; df++)
      #pragma unroll
      for (int r = 0; r < 4; r++) {
        int t = qi*16 + g*4 + r;
        int d = df*16 + rr;
        outb[(size_t)(w*64 + t)*512 + head*32 + d] = f2bf(o[qi][df][r] * inv[qi][r]);
      }
}

extern "C" void kernel_launch(void* const* d_in, const int* in_sizes, int n_in,
                              void* d_out, int out_size, void* d_ws, size_t ws_size,
                              hipStream_t stream) {
  const float* x     = (const float*)d_in[0];
  const float* ln1w  = (const float*)d_in[1];
  const float* ln1b  = (const float*)d_in[2];
  const float* qkvw  = (const float*)d_in[3];
  const float* qkvb  = (const float*)d_in[4];
  const float* rpb   = (const float*)d_in[5];
  const float* projw = (const float*)d_in[6];
  const float* projb = (const float*)d_in[7];
  const float* ln2w  = (const float*)d_in[8];
  const float* ln2b  = (const float*)d_in[9];
  const float* fc1w  = (const float*)d_in[10];
  const float* fc1b  = (const float*)d_in[11];
  const float* fc2w  = (const float*)d_in[12];
  const float* fc2b  = (const float*)d_in[13];
  float* out = (float*)d_out;

  char* ws = (char*)d_ws;
  u16* wqkv  = (u16*)(ws + 0);         // 786432 el
  u16* wproj = (u16*)(ws + 1572864);   // 262144 el
  u16* wfc1  = (u16*)(ws + 2097152);   // 1048576 el
  u16* wfc2  = (u16*)(ws + 4194304);   // 1048576 el
  size_t base = 8ull << 20;
  u16* xw = (u16*)(ws + base);                      // 64 MiB  (aliased later: attn, z)
  u16* qb = (u16*)(ws + base + (64ull  << 20));     // 64 MiB  (aliased later: part of h)
  u16* kb = (u16*)(ws + base + (128ull << 20));     // 64 MiB
  u16* vb = (u16*)(ws + base + (192ull << 20));     // 64 MiB
  u16* attnb = xw;
  u16* zb    = xw;
  u16* hb    = qb;                                  // 256 MiB -> ws end 328 MiB

  // weights -> bf16
  cvt_bf16<<<768,  256, 0, stream>>>((const float4*)qkvw,  (us4*)wqkv,  196608);
  cvt_bf16<<<256,  256, 0, stream>>>((const float4*)projw, (us4*)wproj, 65536);
  cvt_bf16<<<1024, 256, 0, stream>>>((const float4*)fc1w,  (us4*)wfc1,  262144);
  cvt_bf16<<<1024, 256, 0, stream>>>((const float4*)fc2w,  (us4*)wfc2,  262144);

  // LN1 + roll + window partition
  ln_kernel<true><<<16384, 256, 0, stream>>>(x, ln1w, ln1b, xw);
  // QKV
  gemm_k<0><<<512*12, 256, 0, stream>>>(xw, wqkv, qkvb, qb, kb, vb, nullptr, nullptr,
                                        65536, 1536, 512);
  // attention
  attn_k<<<4096, 256, 0, stream>>>(qb, kb, vb, rpb, attnb);
  // proj + win_reverse + residual -> d_out (= x2)
  gemm_k<1><<<512*4, 256, 0, stream>>>(attnb, wproj, projb, nullptr, nullptr, nullptr,
                                       out, x, 65536, 512, 512);
  // LN2
  ln_kernel<false><<<16384, 256, 0, stream>>>(out, ln2w, ln2b, zb);
  // fc1 + gelu
  gemm_k<2><<<512*16, 256, 0, stream>>>(zb, wfc1, fc1b, hb, nullptr, nullptr, nullptr, nullptr,
                                        65536, 2048, 512);
  // fc2 + residual (in-place on d_out)
  gemm_k<3><<<512*4, 256, 0, stream>>>(hb, wfc2, fc2b, nullptr, nullptr, nullptr, out, nullptr,
                                       65536, 512, 2048);
}

// Round 3
// 1059.251 us; speedup vs baseline: 1.1238x; 1.0986x over previous
//
#include <hip/hip_runtime.h>
#include <math.h>

typedef short short8 __attribute__((ext_vector_type(8)));
typedef float f32x4 __attribute__((ext_vector_type(4)));
typedef unsigned short u16;
typedef u16 us4 __attribute__((ext_vector_type(4)));

#define DEVI static __device__ __forceinline__

constexpr float SCALE_Q = 0.17677669529663687f;  // 32^-0.5

DEVI u16 f2bf(float f) {
  unsigned u = __builtin_bit_cast(unsigned, f);
  u += 0x7FFFu + ((u >> 16) & 1u);
  return (u16)(u >> 16);
}

// async global->LDS, 16B per lane; lds dest = wave-uniform base + lane*16
DEVI void gload16(const u16* g, u16* l) {
  __builtin_amdgcn_global_load_lds((const __attribute__((address_space(1))) void*)g,
                                   (__attribute__((address_space(3))) void*)l,
                                   16, 0, 0);
}

// ---------------- weight fp32 -> bf16 ----------------
__global__ void cvt_bf16(const float4* __restrict__ src, us4* __restrict__ dst, int n4) {
  int i = blockIdx.x * 256 + threadIdx.x;
  if (i < n4) {
    float4 v = src[i];
    us4 o = { f2bf(v.x), f2bf(v.y), f2bf(v.z), f2bf(v.w) };
    dst[i] = o;
  }
}

// qkv weights: permute rows so out col' = which*512 + head*32 + d  (src col = head*96 + d*3 + which)
__global__ void cvt_qkvw(const float4* __restrict__ src, us4* __restrict__ dst) {
  int i = blockIdx.x * 256 + threadIdx.x;   // 1536 rows x 128 float4
  int row = i >> 7, c4 = i & 127;
  int which = row >> 9, head = (row >> 5) & 15, d = row & 31;
  int srow = head * 96 + d * 3 + which;
  float4 v = src[srow * 128 + c4];
  us4 o = { f2bf(v.x), f2bf(v.y), f2bf(v.z), f2bf(v.w) };
  dst[i] = o;
}

__global__ void perm_qkvb(const float* __restrict__ src, float* __restrict__ dst) {
  int i = blockIdx.x * 256 + threadIdx.x;   // 1536
  int which = i >> 9, head = (i >> 5) & 15, d = i & 31;
  dst[i] = src[head * 96 + d * 3 + which];
}

// ---------------- LayerNorm (+ optional roll + dilated window partition) ----------------
template<bool PERM>
__global__ __launch_bounds__(256) void ln_kernel(const float* __restrict__ src,
                                                 const float* __restrict__ gw,
                                                 const float* __restrict__ gb,
                                                 u16* __restrict__ dst) {
  int wid = threadIdx.x >> 6, lane = threadIdx.x & 63;
  int m = blockIdx.x * 4 + wid;
  int srow;
  if (PERM) {
    int b = m >> 12;
    int win = (m >> 6) & 63, t = m & 63;
    int i2 = win >> 3, j2 = win & 7, s1 = t >> 3, s2 = t & 7;
    int h = (s1 * 8 + i2 + 4) & 63, w = (s2 * 8 + j2 + 4) & 63;
    srow = (b << 12) + h * 64 + w;
  } else {
    srow = m;
  }
  const float4* r4 = (const float4*)(src + (size_t)srow * 512);
  float4 v0 = r4[lane], v1 = r4[lane + 64];
  float s  = v0.x + v0.y + v0.z + v0.w + v1.x + v1.y + v1.z + v1.w;
  float ss = v0.x*v0.x + v0.y*v0.y + v0.z*v0.z + v0.w*v0.w
           + v1.x*v1.x + v1.y*v1.y + v1.z*v1.z + v1.w*v1.w;
  #pragma unroll
  for (int off = 1; off < 64; off <<= 1) {
    s  += __shfl_xor(s, off);
    ss += __shfl_xor(ss, off);
  }
  float mean = s * (1.f/512.f);
  float var  = ss * (1.f/512.f) - mean*mean;
  float rstd = rsqrtf(var + 1e-5f);
  const float4* w4 = (const float4*)gw;
  const float4* b4 = (const float4*)gb;
  float4 wa = w4[lane], ba = b4[lane], wb = w4[lane+64], bb = b4[lane+64];
  us4 o0 = { f2bf((v0.x-mean)*rstd*wa.x + ba.x),
             f2bf((v0.y-mean)*rstd*wa.y + ba.y),
             f2bf((v0.z-mean)*rstd*wa.z + ba.z),
             f2bf((v0.w-mean)*rstd*wa.w + ba.w) };
  us4 o1 = { f2bf((v1.x-mean)*rstd*wb.x + bb.x),
             f2bf((v1.y-mean)*rstd*wb.y + bb.y),
             f2bf((v1.z-mean)*rstd*wb.z + bb.z),
             f2bf((v1.w-mean)*rstd*wb.w + bb.w) };
  us4* d4 = (us4*)(dst + (size_t)m * 512);
  d4[lane] = o0; d4[lane + 64] = o1;
}

// ---------------- GEMM: C[M,N] = A[M,K](bf16) @ W[N,K]^T(bf16) + bias ----
// 128x128 tile, BK=32, double-buffered LDS (T3-min recipe), global_load_lds, XCD swizzle.
// MODE 0: qkv (permuted cols: tn 0-3 q row-major scaled, 4-7 k row-major, 8-11 v transposed)
//         bf16 outputs bounced through LDS for coalesced dwordx4 stores.
// MODE 1: proj: fo[win_reverse(row), col] = resid[same] + val (fp32 direct)
// MODE 2: fc1: gelu -> o0 bf16 row-major via LDS bounce
// MODE 3: fc2: fo[row*512+col] += val (fp32 direct)
template<int MODE>
__global__ __launch_bounds__(256) void gemm_k(const u16* __restrict__ A,
                                              const u16* __restrict__ Bw,
                                              const float* __restrict__ bias,
                                              u16* __restrict__ o0, u16* __restrict__ o1,
                                              u16* __restrict__ o2,
                                              float* __restrict__ fo,
                                              const float* __restrict__ resid,
                                              int M, int N, int K) {
  __shared__ u16 LDSU[2][2][128][32];   // [buf][op A/B][row][k] = 32 KiB
  int nt = N >> 7;
  int nwg = gridDim.x;
  int cpx = nwg >> 3;
  int bid = blockIdx.x;
  int swz = (bid & 7) * cpx + (bid >> 3);
  int tm = swz / nt, tn = swz % nt;
  int tid = threadIdx.x;
  int lane = tid & 63, wv = tid >> 6;
  int wm = wv >> 1, wn = wv & 1;

  int rA = tid >> 2;
  int c8 = (tid & 3) << 3;
  const u16* ag = A  + (size_t)(tm * 128 + rA) * K + c8;
  const u16* bg = Bw + (size_t)(tn * 128 + rA) * K + c8;
  size_t k64 = (size_t)64 * K;

  f32x4 acc[4][4] = {};
  int rr = lane & 15, g8 = (lane >> 4) << 3;
  int NT = K >> 5;

  // prologue: stage tile 0 into buf 0
  {
    u16* ab = &LDSU[0][0][0][0] + wv * 512;
    u16* bb = &LDSU[0][1][0][0] + wv * 512;
    gload16(ag, ab); gload16(ag + k64, ab + 2048);
    gload16(bg, bb); gload16(bg + k64, bb + 2048);
    ag += 32; bg += 32;
  }
  __syncthreads();

  for (int t = 0; t < NT; ++t) {
    int cur = t & 1;
    if (t + 1 < NT) {   // issue next-tile loads first (hidden under this tile's compute)
      u16* ab = &LDSU[cur ^ 1][0][0][0] + wv * 512;
      u16* bb = &LDSU[cur ^ 1][1][0][0] + wv * 512;
      gload16(ag, ab); gload16(ag + k64, ab + 2048);
      gload16(bg, bb); gload16(bg + k64, bb + 2048);
      ag += 32; bg += 32;
    }
    short8 af[4], bf[4];
    #pragma unroll
    for (int i = 0; i < 4; i++) af[i] = *(const short8*)(&LDSU[cur][0][wm*64 + i*16 + rr][g8]);
    #pragma unroll
    for (int i = 0; i < 4; i++) bf[i] = *(const short8*)(&LDSU[cur][1][wn*64 + i*16 + rr][g8]);
    #pragma unroll
    for (int mi = 0; mi < 4; mi++)
      #pragma unroll
      for (int ni = 0; ni < 4; ni++)
        acc[mi][ni] = __builtin_amdgcn_mfma_f32_16x16x32_bf16(af[mi], bf[ni], acc[mi][ni], 0, 0, 0);
    __syncthreads();   // drains vmcnt: next tile landed; all reads of cur done
  }

  if (MODE == 0 || MODE == 2) {
    // ---- LDS bounce epilogue: coalesced bf16 stores ----
    bool isV = (MODE == 0) && (tn >= 8);
    bool isQ = (MODE == 0) && (tn < 4);
    u16 (*LB)[136] = (u16(*)[136]) & LDSU[0][0][0][0];  // 64 x 136 <= 16384 u16
    int g4 = (lane >> 4) << 2;
    #pragma unroll
    for (int rnd = 0; rnd < 2; ++rnd) {
      if (!isV) {
        if (wm == rnd) {
          #pragma unroll
          for (int ni = 0; ni < 4; ni++) {
            int col = wn*64 + ni*16 + rr;
            float bv = bias[tn*128 + col];
            #pragma unroll
            for (int mi = 0; mi < 4; mi++)
              #pragma unroll
              for (int r = 0; r < 4; r++) {
                float val = acc[mi][ni][r] + bv;
                if (MODE == 2) val = 0.5f * val * (1.f + erff(val * 0.70710678118654752f));
                if (isQ) val *= SCALE_Q;
                LB[mi*16 + g4 + r][col] = f2bf(val);
              }
          }
        }
      } else {
        if (wn == rnd) {
          #pragma unroll
          for (int ni = 0; ni < 4; ni++) {
            int lrow = ni*16 + rr;
            float bv = bias[tn*128 + rnd*64 + lrow];
            #pragma unroll
            for (int mi = 0; mi < 4; mi++)
              #pragma unroll
              for (int r = 0; r < 4; r++)
                LB[lrow][wm*64 + mi*16 + g4 + r] = f2bf(acc[mi][ni][r] + bv);
          }
        }
      }
      __syncthreads();
      int lrow = tid >> 2;
      #pragma unroll
      for (int cc = 0; cc < 4; ++cc) {
        int chunk = (tid & 3) + cc * 4;
        short8 vd = *(const short8*)&LB[lrow][chunk * 8];
        if (MODE == 2) {
          size_t row = (size_t)tm * 128 + rnd * 64 + lrow;
          *(short8*)(o0 + row * N + tn * 128 + chunk * 8) = vd;
        } else if (!isV) {
          int w = tm * 2 + rnd;
          int head = (tn & 3) * 4 + (chunk >> 2);
          u16* dst = (tn < 4) ? o0 : o1;
          *(short8*)(dst + ((size_t)(w * 16 + head) * 64 + lrow) * 32 + (chunk & 3) * 8) = vd;
        } else {
          int cpos = rnd * 64 + lrow;
          int head = (tn - 8) * 4 + (cpos >> 5);
          int d = cpos & 31;
          int w = tm * 2 + (chunk >> 3);
          *(short8*)(o2 + ((size_t)(w * 16 + head) * 32 + d) * 64 + (chunk & 7) * 8) = vd;
        }
      }
      __syncthreads();
    }
  } else {
    // ---- direct fp32 epilogues (64B-coalesced across 16 lanes) ----
    int rb = tm*128 + wm*64 + ((lane >> 4) << 2);
    int cb = tn*128 + wn*64 + rr;
    #pragma unroll
    for (int ni = 0; ni < 4; ni++) {
      int col = cb + ni*16;
      float bv = bias[col];
      #pragma unroll
      for (int mi = 0; mi < 4; mi++) {
        #pragma unroll
        for (int r = 0; r < 4; r++) {
          int row = rb + mi*16 + r;
          float val = acc[mi][ni][r] + bv;
          if (MODE == 1) {
            int w = row >> 6, t = row & 63;
            int b = w >> 6, win = w & 63;
            int i2 = win >> 3, j2 = win & 7, s1 = t >> 3, s2 = t & 7;
            int pos = (b << 12) + (s1*8 + i2)*64 + (s2*8 + j2);
            size_t idx = (size_t)pos * 512 + col;
            fo[idx] = resid[idx] + val;
          } else {
            size_t idx = (size_t)row * 512 + col;
            fo[idx] += val;
          }
        }
      }
    }
  }
}

// ---------------- attention: one wave per (window, head) ----------------
DEVI int zone1(int x) { return x < 56 ? 0 : (x < 60 ? 1 : 2); }

__global__ __launch_bounds__(256) void attn_k(const u16* __restrict__ qb,
                                              const u16* __restrict__ kb,
                                              const u16* __restrict__ vtb,
                                              const float* __restrict__ rpb,
                                              u16* __restrict__ outb) {
  __shared__ u16 P[4][64][72];
  int wid = threadIdx.x >> 6, lane = threadIdx.x & 63;
  int p = blockIdx.x * 4 + wid;
  int w = p >> 4, head = p & 15;
  const u16* qq = qb  + (size_t)p * 2048;
  const u16* kk = kb  + (size_t)p * 2048;
  const u16* vv = vtb + (size_t)p * 2048;
  int rr = lane & 15, g = lane >> 4;

  short8 qf[4], kf[4];
  #pragma unroll
  for (int i = 0; i < 4; i++) qf[i] = *(const short8*)(qq + (i*16 + rr)*32 + g*8);
  #pragma unroll
  for (int i = 0; i < 4; i++) kf[i] = *(const short8*)(kk + (i*16 + rr)*32 + g*8);

  f32x4 zero = {0.f, 0.f, 0.f, 0.f};
  f32x4 s[4][4];
  #pragma unroll
  for (int qi = 0; qi < 4; qi++)
    #pragma unroll
    for (int kj = 0; kj < 4; kj++)
      s[qi][kj] = __builtin_amdgcn_mfma_f32_16x16x32_bf16(qf[qi], kf[kj], zero, 0, 0, 0);

  int win = w & 63, i2 = win >> 3, j2 = win & 7;
  #pragma unroll
  for (int qi = 0; qi < 4; qi++) {
    #pragma unroll
    for (int r = 0; r < 4; r++) {
      int i = qi*16 + g*4 + r;
      int s1i = i >> 3, s2i = i & 7;
      int zi = zone1(s1i*8 + i2)*3 + zone1(s2i*8 + j2);
      #pragma unroll
      for (int kj = 0; kj < 4; kj++) {
        int j = kj*16 + rr;
        int s1j = j >> 3, s2j = j & 7;
        float bv = rpb[((s1i - s1j + 7)*15 + (s2i - s2j + 7))*16 + head];
        int zj = zone1(s1j*8 + i2)*3 + zone1(s2j*8 + j2);
        s[qi][kj][r] += bv + (zi != zj ? -1e10f : 0.f);
      }
    }
  }

  float inv[4][4];
  #pragma unroll
  for (int qi = 0; qi < 4; qi++) {
    #pragma unroll
    for (int r = 0; r < 4; r++) {
      float mx = fmaxf(fmaxf(s[qi][0][r], s[qi][1][r]), fmaxf(s[qi][2][r], s[qi][3][r]));
      mx = fmaxf(mx, __shfl_xor(mx, 1));
      mx = fmaxf(mx, __shfl_xor(mx, 2));
      mx = fmaxf(mx, __shfl_xor(mx, 4));
      mx = fmaxf(mx, __shfl_xor(mx, 8));
      float sum = 0.f;
      #pragma unroll
      for (int kj = 0; kj < 4; kj++) {
        float e = __expf(s[qi][kj][r] - mx);
        s[qi][kj][r] = e;
        sum += e;
      }
      sum += __shfl_xor(sum, 1);
      sum += __shfl_xor(sum, 2);
      sum += __shfl_xor(sum, 4);
      sum += __shfl_xor(sum, 8);
      inv[qi][r] = 1.f / sum;
    }
  }

  #pragma unroll
  for (int qi = 0; qi < 4; qi++)
    #pragma unroll
    for (int kj = 0; kj < 4; kj++)
      #pragma unroll
      for (int r = 0; r < 4; r++)
        P[wid][qi*16 + g*4 + r][kj*16 + rr] = f2bf(s[qi][kj][r]);

  f32x4 o[4][2] = {};
  #pragma unroll
  for (int jh = 0; jh < 2; jh++) {
    short8 vf[2];
    #pragma unroll
    for (int df = 0; df < 2; df++)
      vf[df] = *(const short8*)(vv + (size_t)(df*16 + rr)*64 + jh*32 + g*8);
    #pragma unroll
    for (int qi = 0; qi < 4; qi++) {
      short8 pf = *(const short8*)(&P[wid][qi*16 + rr][jh*32 + g*8]);
      #pragma unroll
      for (int df = 0; df < 2; df++)
        o[qi][df] = __builtin_amdgcn_mfma_f32_16x16x32_bf16(pf, vf[df], o[qi][df], 0, 0, 0);
    }
  }

  #pragma unroll
  for (int qi = 0; qi < 4; qi++)
    #pragma unroll
    for (int df = 0; df < 2; df++)
      #pragma unroll
      for (int r = 0; r < 4; r++) {
        int t = qi*16 + g*4 + r;
        int d = df*16 + rr;
        outb[(size_t)(w*64 + t)*512 + head*32 + d] = f2bf(o[qi][df][r] * inv[qi][r]);
      }
}

extern "C" void kernel_launch(void* const* d_in, const int* in_sizes, int n_in,
                              void* d_out, int out_size, void* d_ws, size_t ws_size,
                              hipStream_t stream) {
  const float* x     = (const float*)d_in[0];
  const float* ln1w  = (const float*)d_in[1];
  const float* ln1b  = (const float*)d_in[2];
  const float* qkvw  = (const float*)d_in[3];
  const float* qkvb  = (const float*)d_in[4];
  const float* rpb   = (const float*)d_in[5];
  const float* projw = (const float*)d_in[6];
  const float* projb = (const float*)d_in[7];
  const float* ln2w  = (const float*)d_in[8];
  const float* ln2b  = (const float*)d_in[9];
  const float* fc1w  = (const float*)d_in[10];
  const float* fc1b  = (const float*)d_in[11];
  const float* fc2w  = (const float*)d_in[12];
  const float* fc2b  = (const float*)d_in[13];
  float* out = (float*)d_out;

  char* ws = (char*)d_ws;
  u16* wqkv  = (u16*)(ws + 0);         // 786432 el (permuted cols)
  u16* wproj = (u16*)(ws + 1572864);   // 262144 el
  u16* wfc1  = (u16*)(ws + 2097152);   // 1048576 el
  u16* wfc2  = (u16*)(ws + 4194304);   // 1048576 el
  float* pb  = (float*)(ws + 6291456); // 1536 el (permuted qkv bias)
  size_t base = 8ull << 20;
  u16* xw = (u16*)(ws + base);                      // 64 MiB  (aliased later: attn, z)
  u16* qb = (u16*)(ws + base + (64ull  << 20));     // 64 MiB  (aliased later: part of h)
  u16* kb = (u16*)(ws + base + (128ull << 20));     // 64 MiB
  u16* vb = (u16*)(ws + base + (192ull << 20));     // 64 MiB
  u16* attnb = xw;
  u16* zb    = xw;
  u16* hb    = qb;                                  // 256 MiB -> ws end 328 MiB

  // weights -> bf16 (qkv permuted)
  cvt_qkvw<<<768, 256, 0, stream>>>((const float4*)qkvw, (us4*)wqkv);
  perm_qkvb<<<6, 256, 0, stream>>>(qkvb, pb);
  cvt_bf16<<<256,  256, 0, stream>>>((const float4*)projw, (us4*)wproj, 65536);
  cvt_bf16<<<1024, 256, 0, stream>>>((const float4*)fc1w,  (us4*)wfc1,  262144);
  cvt_bf16<<<1024, 256, 0, stream>>>((const float4*)fc2w,  (us4*)wfc2,  262144);

  // LN1 + roll + window partition
  ln_kernel<true><<<16384, 256, 0, stream>>>(x, ln1w, ln1b, xw);
  // QKV
  gemm_k<0><<<512*12, 256, 0, stream>>>(xw, wqkv, pb, qb, kb, vb, nullptr, nullptr,
                                        65536, 1536, 512);
  // attention
  attn_k<<<4096, 256, 0, stream>>>(qb, kb, vb, rpb, attnb);
  // proj + win_reverse + residual -> d_out (= x2)
  gemm_k<1><<<512*4, 256, 0, stream>>>(attnb, wproj, projb, nullptr, nullptr, nullptr,
                                       out, x, 65536, 512, 512);
  // LN2
  ln_kernel<false><<<16384, 256, 0, stream>>>(out, ln2w, ln2b, zb);
  // fc1 + gelu
  gemm_k<2><<<512*16, 256, 0, stream>>>(zb, wfc1, fc1b, hb, nullptr, nullptr, nullptr, nullptr,
                                        65536, 2048, 512);
  // fc2 + residual (in-place on d_out)
  gemm_k<3><<<512*4, 256, 0, stream>>>(hb, wfc2, fc2b, nullptr, nullptr, nullptr, out, nullptr,
                                       65536, 512, 2048);
}

// Round 4
// 1019.368 us; speedup vs baseline: 1.1678x; 1.0391x over previous
//
#include <hip/hip_runtime.h>
#include <math.h>

typedef short short8 __attribute__((ext_vector_type(8)));
typedef float f32x4 __attribute__((ext_vector_type(4)));
typedef unsigned short u16;
typedef u16 us4 __attribute__((ext_vector_type(4)));

#define DEVI static __device__ __forceinline__

constexpr float SCALE_Q = 0.17677669529663687f;  // 32^-0.5

DEVI u16 f2bf(float f) {
  unsigned u = __builtin_bit_cast(unsigned, f);
  u += 0x7FFFu + ((u >> 16) & 1u);
  return (u16)(u >> 16);
}

// async global->LDS, 16B per lane; lds dest = wave-uniform base + lane*16
DEVI void gload16(const u16* g, u16* l) {
  __builtin_amdgcn_global_load_lds((const __attribute__((address_space(1))) void*)g,
                                   (__attribute__((address_space(3))) void*)l,
                                   16, 0, 0);
}

// ---------------- weight fp32 -> bf16 ----------------
__global__ void cvt_bf16(const float4* __restrict__ src, us4* __restrict__ dst, int n4) {
  int i = blockIdx.x * 256 + threadIdx.x;
  if (i < n4) {
    float4 v = src[i];
    us4 o = { f2bf(v.x), f2bf(v.y), f2bf(v.z), f2bf(v.w) };
    dst[i] = o;
  }
}

// qkv weights: permute rows so out col' = which*512 + head*32 + d  (src col = head*96 + d*3 + which)
__global__ void cvt_qkvw(const float4* __restrict__ src, us4* __restrict__ dst) {
  int i = blockIdx.x * 256 + threadIdx.x;   // 1536 rows x 128 float4
  int row = i >> 7, c4 = i & 127;
  int which = row >> 9, head = (row >> 5) & 15, d = row & 31;
  int srow = head * 96 + d * 3 + which;
  float4 v = src[srow * 128 + c4];
  us4 o = { f2bf(v.x), f2bf(v.y), f2bf(v.z), f2bf(v.w) };
  dst[i] = o;
}

__global__ void perm_qkvb(const float* __restrict__ src, float* __restrict__ dst) {
  int i = blockIdx.x * 256 + threadIdx.x;   // 1536
  int which = i >> 9, head = (i >> 5) & 15, d = i & 31;
  dst[i] = src[head * 96 + d * 3 + which];
}

// ---------------- LayerNorm (+ optional roll + dilated window partition) ----------------
template<bool PERM>
__global__ __launch_bounds__(256) void ln_kernel(const float* __restrict__ src,
                                                 const float* __restrict__ gw,
                                                 const float* __restrict__ gb,
                                                 u16* __restrict__ dst) {
  int wid = threadIdx.x >> 6, lane = threadIdx.x & 63;
  int m = blockIdx.x * 4 + wid;
  int srow;
  if (PERM) {
    int b = m >> 12;
    int win = (m >> 6) & 63, t = m & 63;
    int i2 = win >> 3, j2 = win & 7, s1 = t >> 3, s2 = t & 7;
    int h = (s1 * 8 + i2 + 4) & 63, w = (s2 * 8 + j2 + 4) & 63;
    srow = (b << 12) + h * 64 + w;
  } else {
    srow = m;
  }
  const float4* r4 = (const float4*)(src + (size_t)srow * 512);
  float4 v0 = r4[lane], v1 = r4[lane + 64];
  float s  = v0.x + v0.y + v0.z + v0.w + v1.x + v1.y + v1.z + v1.w;
  float ss = v0.x*v0.x + v0.y*v0.y + v0.z*v0.z + v0.w*v0.w
           + v1.x*v1.x + v1.y*v1.y + v1.z*v1.z + v1.w*v1.w;
  #pragma unroll
  for (int off = 1; off < 64; off <<= 1) {
    s  += __shfl_xor(s, off);
    ss += __shfl_xor(ss, off);
  }
  float mean = s * (1.f/512.f);
  float var  = ss * (1.f/512.f) - mean*mean;
  float rstd = rsqrtf(var + 1e-5f);
  const float4* w4 = (const float4*)gw;
  const float4* b4 = (const float4*)gb;
  float4 wa = w4[lane], ba = b4[lane], wb = w4[lane+64], bb = b4[lane+64];
  us4 o0 = { f2bf((v0.x-mean)*rstd*wa.x + ba.x),
             f2bf((v0.y-mean)*rstd*wa.y + ba.y),
             f2bf((v0.z-mean)*rstd*wa.z + ba.z),
             f2bf((v0.w-mean)*rstd*wa.w + ba.w) };
  us4 o1 = { f2bf((v1.x-mean)*rstd*wb.x + bb.x),
             f2bf((v1.y-mean)*rstd*wb.y + bb.y),
             f2bf((v1.z-mean)*rstd*wb.z + bb.z),
             f2bf((v1.w-mean)*rstd*wb.w + bb.w) };
  us4* d4 = (us4*)(dst + (size_t)m * 512);
  d4[lane] = o0; d4[lane + 64] = o1;
}

// ---------------- GEMM: C[M,N] = A[M,K](bf16) @ W[N,K]^T(bf16) + bias ----
// 256x256 tile, BK=64, 8 waves (2Mx4N), 128KiB LDS double-buffer.
// One raw s_barrier + one vmcnt(0) per K-tile; tile t+1 staged right after
// barrier(t) and drained at barrier(t+1) -> loads span a full K-tile of compute.
// T2: chunk-XOR LDS swizzle (stage-source pre-swizzled, ds_read swizzled).
// MODE 0: qkv (permuted cols: tn 0-1 q(scaled), 2-3 k, 4-5 v(transposed))
// MODE 1: proj: fo[win_reverse(row), col] = resid[same] + val (fp32 direct)
// MODE 2: fc1: gelu -> o0 bf16 row-major
// MODE 3: fc2: fo[row*512+col] += val (fp32 direct)
template<int MODE>
__global__ __launch_bounds__(512, 2) void gemm_k(const u16* __restrict__ A,
                                                 const u16* __restrict__ Bw,
                                                 const float* __restrict__ bias,
                                                 u16* __restrict__ o0, u16* __restrict__ o1,
                                                 u16* __restrict__ o2,
                                                 float* __restrict__ fo,
                                                 const float* __restrict__ resid,
                                                 int M, int N, int K) {
  __shared__ u16 LDS2[2][2][16384];   // [buf][A/B][256 rows x 64 cols] = 128 KiB
  int nt = N >> 8;
  int nwg = gridDim.x;
  int cpx = nwg >> 3;
  int bid = blockIdx.x;
  int swz = (bid & 7) * cpx + (bid >> 3);
  int tm = swz / nt, tn = swz % nt;
  int tid = threadIdx.x;
  int lane = tid & 63, wv = tid >> 6;
  int wm = wv >> 2, wn = wv & 3;       // 2 M-halves x 4 N-quarters
  int rr = lane & 15, g = lane >> 4;

  // per-lane staging sources (chunk pre-XORed so linear LDS dest + swizzled read match)
  const u16* asrc[4]; const u16* bsrc[4];
  #pragma unroll
  for (int l = 0; l < 4; l++) {
    int idx = l * 512 + tid;
    int r = idx >> 3, ch = idx & 7;
    int cs = (ch ^ (r & 7)) * 8;
    asrc[l] = A  + (size_t)(tm * 256 + r) * K + cs;
    bsrc[l] = Bw + (size_t)(tn * 256 + r) * K + cs;
  }
  int NT = K >> 6;

  // prologue: stage tile 0 -> buf 0
  #pragma unroll
  for (int l = 0; l < 4; l++) {
    gload16(asrc[l], &LDS2[0][0][(l * 512 + wv * 64) * 8]);
    gload16(bsrc[l], &LDS2[0][1][(l * 512 + wv * 64) * 8]);
  }

  f32x4 acc[8][4] = {};

  for (int t = 0; t < NT; ++t) {
    int cur = t & 1;
    asm volatile("s_waitcnt vmcnt(0)" ::: "memory");   // tile t landed (issued 1 tile ago)
    __builtin_amdgcn_s_barrier();                      // publish; prefetch dest now dead
    const u16* AT = &LDS2[cur][0][0];
    const u16* BT = &LDS2[cur][1][0];
    short8 bfr[4][2];
    #pragma unroll
    for (int q = 0; q < 4; q++) {
      if (q < 2 && t + 1 < NT) {                       // stage tile t+1 early (quads 0,1)
        int koff = (t + 1) * 64;
        #pragma unroll
        for (int h = 0; h < 2; h++) {
          int l = q * 2 + h;
          gload16(asrc[l] + koff, &LDS2[cur ^ 1][0][(l * 512 + wv * 64) * 8]);
          gload16(bsrc[l] + koff, &LDS2[cur ^ 1][1][(l * 512 + wv * 64) * 8]);
        }
      }
      if (q == 0) {
        #pragma unroll
        for (int ni = 0; ni < 4; ni++)
          #pragma unroll
          for (int ks = 0; ks < 2; ks++) {
            int r = wn * 64 + ni * 16 + rr;
            bfr[ni][ks] = *(const short8*)(BT + r * 64 + (((ks * 4 + g) ^ (r & 7)) * 8));
          }
      }
      short8 af[2][2];
      #pragma unroll
      for (int mm = 0; mm < 2; mm++)
        #pragma unroll
        for (int ks = 0; ks < 2; ks++) {
          int r = wm * 128 + (q * 2 + mm) * 16 + rr;
          af[mm][ks] = *(const short8*)(AT + r * 64 + (((ks * 4 + g) ^ (r & 7)) * 8));
        }
      __builtin_amdgcn_s_setprio(1);
      #pragma unroll
      for (int mm = 0; mm < 2; mm++)
        #pragma unroll
        for (int ks = 0; ks < 2; ks++)
          #pragma unroll
          for (int ni = 0; ni < 4; ni++)
            acc[q * 2 + mm][ni] = __builtin_amdgcn_mfma_f32_16x16x32_bf16(
                af[mm][ks], bfr[ni][ks], acc[q * 2 + mm][ni], 0, 0, 0);
      __builtin_amdgcn_s_setprio(0);
    }
  }

  __syncthreads();   // full drain before LDS reuse
  u16* wreg = &LDS2[0][0][0] + wv * 8192;   // wave-private 16 KiB bounce
  int rb0 = tm * 256 + wm * 128;
  int cb0 = tn * 256 + wn * 64;

  if (MODE == 0 || MODE == 2) {
    bool isV = (MODE == 0) && (tn >= 4);
    if (!isV) {
      #pragma unroll
      for (int mi = 0; mi < 8; mi++)
        #pragma unroll
        for (int ni = 0; ni < 4; ni++) {
          float bv = bias[cb0 + ni * 16 + rr];
          #pragma unroll
          for (int r = 0; r < 4; r++) {
            float val = acc[mi][ni][r] + bv;
            if (MODE == 2) val = 0.5f * val * (1.f + erff(val * 0.70710678118654752f));
            if (MODE == 0 && tn < 2) val *= SCALE_Q;
            int row = mi * 16 + g * 4 + r;
            int col = ni * 16 + rr;
            wreg[row * 64 + (((col >> 3) ^ (row & 7)) * 8) + (col & 7)] = f2bf(val);
          }
        }
      #pragma unroll
      for (int rep = 0; rep < 2; rep++) {
        int row = rep * 64 + lane;
        #pragma unroll
        for (int ch = 0; ch < 8; ch++) {
          short8 vd = *(const short8*)&wreg[row * 64 + ((ch ^ (row & 7)) * 8)];
          if (MODE == 2) {
            size_t grow = (size_t)rb0 + row;
            *(short8*)(o0 + grow * N + cb0 + ch * 8) = vd;
          } else {
            int grow = rb0 + row;
            int w = grow >> 6, tt = grow & 63;
            int hb = (cb0 & 511) >> 5;
            int head = hb + (ch >> 2);
            u16* dst = (tn < 2) ? o0 : o1;
            *(short8*)(dst + ((size_t)(w * 16 + head) * 64 + tt) * 32 + (ch & 3) * 8) = vd;
          }
        }
      }
    } else {
      // v: transposed deposit (col-major region), chunk-XOR on row-chunks
      #pragma unroll
      for (int mi = 0; mi < 8; mi++)
        #pragma unroll
        for (int ni = 0; ni < 4; ni++) {
          float bv = bias[cb0 + ni * 16 + rr];
          #pragma unroll
          for (int r = 0; r < 4; r++) {
            float val = acc[mi][ni][r] + bv;
            int row = mi * 16 + g * 4 + r;   // t-dim (0..127)
            int col = ni * 16 + rr;          // d-dim (0..63)
            wreg[col * 128 + (((row >> 3) ^ (col & 7)) * 8) + (row & 7)] = f2bf(val);
          }
        }
      int cb0v = cb0 - 1024;
      int col = lane;
      int head = (cb0v >> 5) + (col >> 5), d = col & 31;
      #pragma unroll
      for (int ch = 0; ch < 16; ch++) {
        short8 vd = *(const short8*)&wreg[col * 128 + ((ch ^ (col & 7)) * 8)];
        int grow = rb0 + ch * 8;
        int w = grow >> 6, t0 = grow & 63;
        *(short8*)(o2 + ((size_t)(w * 16 + head) * 32 + d) * 64 + t0) = vd;
      }
    }
  } else {
    #pragma unroll
    for (int ni = 0; ni < 4; ni++) {
      int col = cb0 + ni * 16 + rr;
      float bv = bias[col];
      #pragma unroll
      for (int mi = 0; mi < 8; mi++) {
        #pragma unroll
        for (int r = 0; r < 4; r++) {
          int row = rb0 + mi * 16 + g * 4 + r;
          float val = acc[mi][ni][r] + bv;
          if (MODE == 1) {
            int w = row >> 6, t = row & 63;
            int b = w >> 6, win = w & 63;
            int i2 = win >> 3, j2 = win & 7, s1 = t >> 3, s2 = t & 7;
            int pos = (b << 12) + (s1 * 8 + i2) * 64 + (s2 * 8 + j2);
            size_t idx = (size_t)pos * 512 + col;
            fo[idx] = resid[idx] + val;
          } else {
            size_t idx = (size_t)row * 512 + col;
            fo[idx] += val;
          }
        }
      }
    }
  }
}

// ---------------- attention: one wave per (window, head) ----------------
DEVI int zone1(int x) { return x < 56 ? 0 : (x < 60 ? 1 : 2); }

__global__ __launch_bounds__(256) void attn_k(const u16* __restrict__ qb,
                                              const u16* __restrict__ kb,
                                              const u16* __restrict__ vtb,
                                              const float* __restrict__ rpb,
                                              u16* __restrict__ outb) {
  __shared__ u16 P[4][64][72];
  int wid = threadIdx.x >> 6, lane = threadIdx.x & 63;
  int p = blockIdx.x * 4 + wid;
  int w = p >> 4, head = p & 15;
  const u16* qq = qb  + (size_t)p * 2048;
  const u16* kk = kb  + (size_t)p * 2048;
  const u16* vv = vtb + (size_t)p * 2048;
  int rr = lane & 15, g = lane >> 4;

  short8 qf[4], kf[4];
  #pragma unroll
  for (int i = 0; i < 4; i++) qf[i] = *(const short8*)(qq + (i*16 + rr)*32 + g*8);
  #pragma unroll
  for (int i = 0; i < 4; i++) kf[i] = *(const short8*)(kk + (i*16 + rr)*32 + g*8);

  f32x4 zero = {0.f, 0.f, 0.f, 0.f};
  f32x4 s[4][4];
  #pragma unroll
  for (int qi = 0; qi < 4; qi++)
    #pragma unroll
    for (int kj = 0; kj < 4; kj++)
      s[qi][kj] = __builtin_amdgcn_mfma_f32_16x16x32_bf16(qf[qi], kf[kj], zero, 0, 0, 0);

  int win = w & 63, i2 = win >> 3, j2 = win & 7;
  #pragma unroll
  for (int qi = 0; qi < 4; qi++) {
    #pragma unroll
    for (int r = 0; r < 4; r++) {
      int i = qi*16 + g*4 + r;
      int s1i = i >> 3, s2i = i & 7;
      int zi = zone1(s1i*8 + i2)*3 + zone1(s2i*8 + j2);
      #pragma unroll
      for (int kj = 0; kj < 4; kj++) {
        int j = kj*16 + rr;
        int s1j = j >> 3, s2j = j & 7;
        float bv = rpb[((s1i - s1j + 7)*15 + (s2i - s2j + 7))*16 + head];
        int zj = zone1(s1j*8 + i2)*3 + zone1(s2j*8 + j2);
        s[qi][kj][r] += bv + (zi != zj ? -1e10f : 0.f);
      }
    }
  }

  float inv[4][4];
  #pragma unroll
  for (int qi = 0; qi < 4; qi++) {
    #pragma unroll
    for (int r = 0; r < 4; r++) {
      float mx = fmaxf(fmaxf(s[qi][0][r], s[qi][1][r]), fmaxf(s[qi][2][r], s[qi][3][r]));
      mx = fmaxf(mx, __shfl_xor(mx, 1));
      mx = fmaxf(mx, __shfl_xor(mx, 2));
      mx = fmaxf(mx, __shfl_xor(mx, 4));
      mx = fmaxf(mx, __shfl_xor(mx, 8));
      float sum = 0.f;
      #pragma unroll
      for (int kj = 0; kj < 4; kj++) {
        float e = __expf(s[qi][kj][r] - mx);
        s[qi][kj][r] = e;
        sum += e;
      }
      sum += __shfl_xor(sum, 1);
      sum += __shfl_xor(sum, 2);
      sum += __shfl_xor(sum, 4);
      sum += __shfl_xor(sum, 8);
      inv[qi][r] = 1.f / sum;
    }
  }

  #pragma unroll
  for (int qi = 0; qi < 4; qi++)
    #pragma unroll
    for (int kj = 0; kj < 4; kj++)
      #pragma unroll
      for (int r = 0; r < 4; r++)
        P[wid][qi*16 + g*4 + r][kj*16 + rr] = f2bf(s[qi][kj][r]);

  f32x4 o[4][2] = {};
  #pragma unroll
  for (int jh = 0; jh < 2; jh++) {
    short8 vf[2];
    #pragma unroll
    for (int df = 0; df < 2; df++)
      vf[df] = *(const short8*)(vv + (size_t)(df*16 + rr)*64 + jh*32 + g*8);
    #pragma unroll
    for (int qi = 0; qi < 4; qi++) {
      short8 pf = *(const short8*)(&P[wid][qi*16 + rr][jh*32 + g*8]);
      #pragma unroll
      for (int df = 0; df < 2; df++)
        o[qi][df] = __builtin_amdgcn_mfma_f32_16x16x32_bf16(pf, vf[df], o[qi][df], 0, 0, 0);
    }
  }

  #pragma unroll
  for (int qi = 0; qi < 4; qi++)
    #pragma unroll
    for (int df = 0; df < 2; df++)
      #pragma unroll
      for (int r = 0; r < 4; r++) {
        int t = qi*16 + g*4 + r;
        int d = df*16 + rr;
        outb[(size_t)(w*64 + t)*512 + head*32 + d] = f2bf(o[qi][df][r] * inv[qi][r]);
      }
}

extern "C" void kernel_launch(void* const* d_in, const int* in_sizes, int n_in,
                              void* d_out, int out_size, void* d_ws, size_t ws_size,
                              hipStream_t stream) {
  const float* x     = (const float*)d_in[0];
  const float* ln1w  = (const float*)d_in[1];
  const float* ln1b  = (const float*)d_in[2];
  const float* qkvw  = (const float*)d_in[3];
  const float* qkvb  = (const float*)d_in[4];
  const float* rpb   = (const float*)d_in[5];
  const float* projw = (const float*)d_in[6];
  const float* projb = (const float*)d_in[7];
  const float* ln2w  = (const float*)d_in[8];
  const float* ln2b  = (const float*)d_in[9];
  const float* fc1w  = (const float*)d_in[10];
  const float* fc1b  = (const float*)d_in[11];
  const float* fc2w  = (const float*)d_in[12];
  const float* fc2b  = (const float*)d_in[13];
  float* out = (float*)d_out;

  char* ws = (char*)d_ws;
  u16* wqkv  = (u16*)(ws + 0);         // 786432 el (permuted cols)
  u16* wproj = (u16*)(ws + 1572864);   // 262144 el
  u16* wfc1  = (u16*)(ws + 2097152);   // 1048576 el
  u16* wfc2  = (u16*)(ws + 4194304);   // 1048576 el
  float* pb  = (float*)(ws + 6291456); // 1536 el (permuted qkv bias)
  size_t base = 8ull << 20;
  u16* xw = (u16*)(ws + base);                      // 64 MiB  (aliased later: attn, z)
  u16* qb = (u16*)(ws + base + (64ull  << 20));     // 64 MiB  (aliased later: part of h)
  u16* kb = (u16*)(ws + base + (128ull << 20));     // 64 MiB
  u16* vb = (u16*)(ws + base + (192ull << 20));     // 64 MiB
  u16* attnb = xw;
  u16* zb    = xw;
  u16* hb    = qb;                                  // 256 MiB -> ws end 328 MiB

  // weights -> bf16 (qkv permuted)
  cvt_qkvw<<<768, 256, 0, stream>>>((const float4*)qkvw, (us4*)wqkv);
  perm_qkvb<<<6, 256, 0, stream>>>(qkvb, pb);
  cvt_bf16<<<256,  256, 0, stream>>>((const float4*)projw, (us4*)wproj, 65536);
  cvt_bf16<<<1024, 256, 0, stream>>>((const float4*)fc1w,  (us4*)wfc1,  262144);
  cvt_bf16<<<1024, 256, 0, stream>>>((const float4*)fc2w,  (us4*)wfc2,  262144);

  // LN1 + roll + window partition
  ln_kernel<true><<<16384, 256, 0, stream>>>(x, ln1w, ln1b, xw);
  // QKV: grid (65536/256) x (1536/256) = 1536
  gemm_k<0><<<1536, 512, 0, stream>>>(xw, wqkv, pb, qb, kb, vb, nullptr, nullptr,
                                      65536, 1536, 512);
  // attention
  attn_k<<<4096, 256, 0, stream>>>(qb, kb, vb, rpb, attnb);
  // proj + win_reverse + residual -> d_out (= x2): 256 x 2 = 512
  gemm_k<1><<<512, 512, 0, stream>>>(attnb, wproj, projb, nullptr, nullptr, nullptr,
                                     out, x, 65536, 512, 512);
  // LN2
  ln_kernel<false><<<16384, 256, 0, stream>>>(out, ln2w, ln2b, zb);
  // fc1 + gelu: 256 x 8 = 2048
  gemm_k<2><<<2048, 512, 0, stream>>>(zb, wfc1, fc1b, hb, nullptr, nullptr, nullptr, nullptr,
                                      65536, 2048, 512);
  // fc2 + residual (in-place on d_out): 256 x 2 = 512
  gemm_k<3><<<512, 512, 0, stream>>>(hb, wfc2, fc2b, nullptr, nullptr, nullptr, out, nullptr,
                                     65536, 512, 2048);
}

// Round 5
// 885.277 us; speedup vs baseline: 1.3446x; 1.1515x over previous
//
#include <hip/hip_runtime.h>
#include <math.h>

typedef short short8 __attribute__((ext_vector_type(8)));
typedef float f32x4 __attribute__((ext_vector_type(4)));
typedef unsigned short u16;
typedef u16 us4 __attribute__((ext_vector_type(4)));

#define DEVI static __device__ __forceinline__

constexpr float SCALE_Q = 0.17677669529663687f;  // 32^-0.5

DEVI u16 f2bf(float f) {
  unsigned u = __builtin_bit_cast(unsigned, f);
  u += 0x7FFFu + ((u >> 16) & 1u);
  return (u16)(u >> 16);
}

// async global->LDS, 16B per lane; lds dest = wave-uniform base + lane*16
DEVI void gload16(const u16* g, u16* l) {
  __builtin_amdgcn_global_load_lds((const __attribute__((address_space(1))) void*)g,
                                   (__attribute__((address_space(3))) void*)l,
                                   16, 0, 0);
}

// ---------------- weight fp32 -> bf16 ----------------
__global__ void cvt_bf16(const float4* __restrict__ src, us4* __restrict__ dst, int n4) {
  int i = blockIdx.x * 256 + threadIdx.x;
  if (i < n4) {
    float4 v = src[i];
    us4 o = { f2bf(v.x), f2bf(v.y), f2bf(v.z), f2bf(v.w) };
    dst[i] = o;
  }
}

// qkv weights: permute rows so out col' = which*512 + head*32 + d  (src col = head*96 + d*3 + which)
__global__ void cvt_qkvw(const float4* __restrict__ src, us4* __restrict__ dst) {
  int i = blockIdx.x * 256 + threadIdx.x;   // 1536 rows x 128 float4
  int row = i >> 7, c4 = i & 127;
  int which = row >> 9, head = (row >> 5) & 15, d = row & 31;
  int srow = head * 96 + d * 3 + which;
  float4 v = src[srow * 128 + c4];
  us4 o = { f2bf(v.x), f2bf(v.y), f2bf(v.z), f2bf(v.w) };
  dst[i] = o;
}

__global__ void perm_qkvb(const float* __restrict__ src, float* __restrict__ dst) {
  int i = blockIdx.x * 256 + threadIdx.x;   // 1536
  int which = i >> 9, head = (i >> 5) & 15, d = i & 31;
  dst[i] = src[head * 96 + d * 3 + which];
}

// ---------------- LayerNorm (+ optional roll + dilated window partition) ----------------
template<bool PERM>
__global__ __launch_bounds__(256) void ln_kernel(const float* __restrict__ src,
                                                 const float* __restrict__ gw,
                                                 const float* __restrict__ gb,
                                                 u16* __restrict__ dst) {
  int wid = threadIdx.x >> 6, lane = threadIdx.x & 63;
  int m = blockIdx.x * 4 + wid;
  int srow;
  if (PERM) {
    int b = m >> 12;
    int win = (m >> 6) & 63, t = m & 63;
    int i2 = win >> 3, j2 = win & 7, s1 = t >> 3, s2 = t & 7;
    int h = (s1 * 8 + i2 + 4) & 63, w = (s2 * 8 + j2 + 4) & 63;
    srow = (b << 12) + h * 64 + w;
  } else {
    srow = m;
  }
  const float4* r4 = (const float4*)(src + (size_t)srow * 512);
  float4 v0 = r4[lane], v1 = r4[lane + 64];
  float s  = v0.x + v0.y + v0.z + v0.w + v1.x + v1.y + v1.z + v1.w;
  float ss = v0.x*v0.x + v0.y*v0.y + v0.z*v0.z + v0.w*v0.w
           + v1.x*v1.x + v1.y*v1.y + v1.z*v1.z + v1.w*v1.w;
  #pragma unroll
  for (int off = 1; off < 64; off <<= 1) {
    s  += __shfl_xor(s, off);
    ss += __shfl_xor(ss, off);
  }
  float mean = s * (1.f/512.f);
  float var  = ss * (1.f/512.f) - mean*mean;
  float rstd = rsqrtf(var + 1e-5f);
  const float4* w4 = (const float4*)gw;
  const float4* b4 = (const float4*)gb;
  float4 wa = w4[lane], ba = b4[lane], wb = w4[lane+64], bb = b4[lane+64];
  us4 o0 = { f2bf((v0.x-mean)*rstd*wa.x + ba.x),
             f2bf((v0.y-mean)*rstd*wa.y + ba.y),
             f2bf((v0.z-mean)*rstd*wa.z + ba.z),
             f2bf((v0.w-mean)*rstd*wa.w + ba.w) };
  us4 o1 = { f2bf((v1.x-mean)*rstd*wb.x + bb.x),
             f2bf((v1.y-mean)*rstd*wb.y + bb.y),
             f2bf((v1.z-mean)*rstd*wb.z + bb.z),
             f2bf((v1.w-mean)*rstd*wb.w + bb.w) };
  us4* d4 = (us4*)(dst + (size_t)m * 512);
  d4[lane] = o0; d4[lane + 64] = o1;
}

// ---------------- GEMM: C[M,N] = A[M,K](bf16) @ W[N,K]^T(bf16) + bias ----
// 256x256 tile, BK=32, 8 waves (2Mx4N), 4-deep LDS ring (4 x 32 KiB).
// 2 phases per K-tile: {stage(kt+3) || ds_read || barrier || lgkm0 || setprio MFMA x16 || barrier}
// Counted vmcnt(8) at tile boundary (never 0 in steady state) - T3+T4+T5.
// Swizzle: chunk = (g + (r>>1)) & 3 on stage-source AND ds_read (64B rows).
// MODE 0: qkv (permuted cols: tn 0-1 q(scaled), 2-3 k, 4-5 v(transposed))
// MODE 1: proj: fo[win_reverse(row), col] = resid[same] + val (fp32 direct)
// MODE 2: fc1: gelu(tanh-approx) -> o0 bf16 row-major
// MODE 3: fc2: fo[row*512+col] += val (fp32 direct)
template<int MODE>
__global__ __launch_bounds__(512, 1) void gemm_k(const u16* __restrict__ A,
                                                 const u16* __restrict__ Bw,
                                                 const float* __restrict__ bias,
                                                 u16* __restrict__ o0, u16* __restrict__ o1,
                                                 u16* __restrict__ o2,
                                                 float* __restrict__ fo,
                                                 const float* __restrict__ resid,
                                                 int M, int N, int K) {
  __shared__ u16 LDS[65536];   // ring: buf c -> A at c*16384, B at c*16384+8192 (u16 units)
  int nt = N >> 8;
  int nwg = gridDim.x, cpx = nwg >> 3, bid = blockIdx.x;
  int swz = (bid & 7) * cpx + (bid >> 3);
  int tm = swz / nt, tn = swz % nt;
  int tid = threadIdx.x, lane = tid & 63, wv = tid >> 6;
  int wm = wv >> 2, wn = wv & 3;       // 2 M-halves x 4 N-quarters
  int rr = lane & 15, g = lane >> 4;
  int NT = K >> 5;

  // staging: thread covers (r = tid>>2, ch = tid&3) and (r+128, ch); src k-chunk = (ch - (r>>1)) & 3
  int rA = tid >> 2, ch = tid & 3;
  int ga = (ch - (rA >> 1)) & 3;
  const u16* a0 = A  + (size_t)(tm * 256 + rA) * K + ga * 8;
  const u16* b0 = Bw + (size_t)(tn * 256 + rA) * K + ga * 8;
  size_t rskip = (size_t)128 * K;

#define STAGE_A(kt) { u16* d = &LDS[(((kt) & 3) << 14) + (wv << 9)]; \
    gload16(a0 + (kt) * 32, d); gload16(a0 + rskip + (kt) * 32, d + 4096); }
#define STAGE_B(kt) { u16* d = &LDS[(((kt) & 3) << 14) + 8192 + (wv << 9)]; \
    gload16(b0 + (kt) * 32, d); gload16(b0 + rskip + (kt) * 32, d + 4096); }

  f32x4 acc[8][4] = {};

  // prologue: stage tiles 0,1,2 (12 loads/thread); wait tile 0 (vmcnt(8))
  STAGE_A(0); STAGE_B(0);
  STAGE_A(1); STAGE_B(1);
  STAGE_A(2); STAGE_B(2);
  asm volatile("s_waitcnt vmcnt(8)" ::: "memory");
  __builtin_amdgcn_s_barrier();

  for (int kt = 0; kt < NT; ++kt) {
    int c = kt & 3;
    const u16* AT = &LDS[c << 14];
    const u16* BT = &LDS[(c << 14) + 8192];
    // ---- phase A: mi 0..3 ----
    if (kt + 3 < NT) STAGE_A(kt + 3);
    short8 bf[4], af[4];
    #pragma unroll
    for (int ni = 0; ni < 4; ni++) {
      int r = wn * 64 + ni * 16 + rr;
      bf[ni] = *(const short8*)(BT + r * 32 + (((g + (r >> 1)) & 3) << 3));
    }
    #pragma unroll
    for (int mi = 0; mi < 4; mi++) {
      int r = wm * 128 + mi * 16 + rr;
      af[mi] = *(const short8*)(AT + r * 32 + (((g + (r >> 1)) & 3) << 3));
    }
    __builtin_amdgcn_s_barrier();
    asm volatile("s_waitcnt lgkmcnt(0)" ::: "memory");
    __builtin_amdgcn_sched_barrier(0);
    __builtin_amdgcn_s_setprio(1);
    #pragma unroll
    for (int mi = 0; mi < 4; mi++)
      #pragma unroll
      for (int ni = 0; ni < 4; ni++)
        acc[mi][ni] = __builtin_amdgcn_mfma_f32_16x16x32_bf16(af[mi], bf[ni], acc[mi][ni], 0, 0, 0);
    __builtin_amdgcn_s_setprio(0);
    __builtin_amdgcn_s_barrier();
    // ---- phase B: mi 4..7 ----
    if (kt + 3 < NT) STAGE_B(kt + 3);
    short8 af2[4];
    #pragma unroll
    for (int mi = 0; mi < 4; mi++) {
      int r = wm * 128 + 64 + mi * 16 + rr;
      af2[mi] = *(const short8*)(AT + r * 32 + (((g + (r >> 1)) & 3) << 3));
    }
    if (kt < NT - 3)      { asm volatile("s_waitcnt vmcnt(8)" ::: "memory"); }
    else if (kt == NT - 3){ asm volatile("s_waitcnt vmcnt(4)" ::: "memory"); }
    else if (kt == NT - 2){ asm volatile("s_waitcnt vmcnt(0)" ::: "memory"); }
    __builtin_amdgcn_s_barrier();
    asm volatile("s_waitcnt lgkmcnt(0)" ::: "memory");
    __builtin_amdgcn_sched_barrier(0);
    __builtin_amdgcn_s_setprio(1);
    #pragma unroll
    for (int mi = 0; mi < 4; mi++)
      #pragma unroll
      for (int ni = 0; ni < 4; ni++)
        acc[4 + mi][ni] = __builtin_amdgcn_mfma_f32_16x16x32_bf16(af2[mi], bf[ni], acc[4 + mi][ni], 0, 0, 0);
    __builtin_amdgcn_s_setprio(0);
    __builtin_amdgcn_s_barrier();
  }
#undef STAGE_A
#undef STAGE_B

  __syncthreads();   // full drain before LDS reuse
  u16* wreg = &LDS[0] + wv * 8192;   // wave-private 16 KiB bounce
  int rb0 = tm * 256 + wm * 128;
  int cb0 = tn * 256 + wn * 64;

  if (MODE == 0 || MODE == 2) {
    bool isV = (MODE == 0) && (tn >= 4);
    if (!isV) {
      #pragma unroll
      for (int mi = 0; mi < 8; mi++)
        #pragma unroll
        for (int ni = 0; ni < 4; ni++) {
          float bv = bias[cb0 + ni * 16 + rr];
          #pragma unroll
          for (int r = 0; r < 4; r++) {
            float val = acc[mi][ni][r] + bv;
            if (MODE == 2) {
              // tanh-approx GELU: val * e/(e+1), e = exp(2*(0.79788456*(val+0.044715 val^3)))
              float u = val * (0.79788456f + 0.03567740814f * val * val);
              float e = __expf(2.f * u);
              val = val * (1.f - __builtin_amdgcn_rcpf(e + 1.f));
            }
            if (MODE == 0 && tn < 2) val *= SCALE_Q;
            int row = mi * 16 + g * 4 + r;
            int col = ni * 16 + rr;
            wreg[row * 64 + (((col >> 3) ^ (row & 7)) * 8) + (col & 7)] = f2bf(val);
          }
        }
      #pragma unroll
      for (int rep = 0; rep < 2; rep++) {
        int row = rep * 64 + lane;
        #pragma unroll
        for (int chk = 0; chk < 8; chk++) {
          short8 vd = *(const short8*)&wreg[row * 64 + ((chk ^ (row & 7)) * 8)];
          if (MODE == 2) {
            size_t grow = (size_t)rb0 + row;
            *(short8*)(o0 + grow * N + cb0 + chk * 8) = vd;
          } else {
            int grow = rb0 + row;
            int w = grow >> 6, tt = grow & 63;
            int hb = (cb0 & 511) >> 5;
            int head = hb + (chk >> 2);
            u16* dst = (tn < 2) ? o0 : o1;
            *(short8*)(dst + ((size_t)(w * 16 + head) * 64 + tt) * 32 + (chk & 3) * 8) = vd;
          }
        }
      }
    } else {
      // v: transposed deposit (d-major), chunk-XOR on row-chunks
      #pragma unroll
      for (int mi = 0; mi < 8; mi++)
        #pragma unroll
        for (int ni = 0; ni < 4; ni++) {
          float bv = bias[cb0 + ni * 16 + rr];
          #pragma unroll
          for (int r = 0; r < 4; r++) {
            float val = acc[mi][ni][r] + bv;
            int row = mi * 16 + g * 4 + r;   // t-dim (0..127)
            int col = ni * 16 + rr;          // d-dim (0..63)
            wreg[col * 128 + (((row >> 3) ^ (col & 7)) * 8) + (row & 7)] = f2bf(val);
          }
        }
      int cb0v = cb0 - 1024;
      int col = lane;
      int head = (cb0v >> 5) + (col >> 5), d = col & 31;
      #pragma unroll
      for (int chk = 0; chk < 16; chk++) {
        short8 vd = *(const short8*)&wreg[col * 128 + ((chk ^ (col & 7)) * 8)];
        int grow = rb0 + chk * 8;
        int w = grow >> 6, t0 = grow & 63;
        *(short8*)(o2 + ((size_t)(w * 16 + head) * 32 + d) * 64 + t0) = vd;
      }
    }
  } else {
    #pragma unroll
    for (int ni = 0; ni < 4; ni++) {
      int col = cb0 + ni * 16 + rr;
      float bv = bias[col];
      #pragma unroll
      for (int mi = 0; mi < 8; mi++) {
        #pragma unroll
        for (int r = 0; r < 4; r++) {
          int row = rb0 + mi * 16 + g * 4 + r;
          float val = acc[mi][ni][r] + bv;
          if (MODE == 1) {
            int w = row >> 6, t = row & 63;
            int b = w >> 6, win = w & 63;
            int i2 = win >> 3, j2 = win & 7, s1 = t >> 3, s2 = t & 7;
            int pos = (b << 12) + (s1 * 8 + i2) * 64 + (s2 * 8 + j2);
            size_t idx = (size_t)pos * 512 + col;
            fo[idx] = resid[idx] + val;
          } else {
            size_t idx = (size_t)row * 512 + col;
            fo[idx] += val;
          }
        }
      }
    }
  }
}

// ---------------- attention: one wave per (window, head) ----------------
DEVI int zone1(int x) { return x < 56 ? 0 : (x < 60 ? 1 : 2); }

__global__ __launch_bounds__(256) void attn_k(const u16* __restrict__ qb,
                                              const u16* __restrict__ kb,
                                              const u16* __restrict__ vtb,
                                              const float* __restrict__ rpb,
                                              u16* __restrict__ outb) {
  __shared__ u16 P[4][64][72];
  int wid = threadIdx.x >> 6, lane = threadIdx.x & 63;
  int p = blockIdx.x * 4 + wid;
  int w = p >> 4, head = p & 15;
  const u16* qq = qb  + (size_t)p * 2048;
  const u16* kk = kb  + (size_t)p * 2048;
  const u16* vv = vtb + (size_t)p * 2048;
  int rr = lane & 15, g = lane >> 4;

  short8 qf[4], kf[4];
  #pragma unroll
  for (int i = 0; i < 4; i++) qf[i] = *(const short8*)(qq + (i*16 + rr)*32 + g*8);
  #pragma unroll
  for (int i = 0; i < 4; i++) kf[i] = *(const short8*)(kk + (i*16 + rr)*32 + g*8);

  f32x4 zero = {0.f, 0.f, 0.f, 0.f};
  f32x4 s[4][4];
  #pragma unroll
  for (int qi = 0; qi < 4; qi++)
    #pragma unroll
    for (int kj = 0; kj < 4; kj++)
      s[qi][kj] = __builtin_amdgcn_mfma_f32_16x16x32_bf16(qf[qi], kf[kj], zero, 0, 0, 0);

  int win = w & 63, i2 = win >> 3, j2 = win & 7;
  #pragma unroll
  for (int qi = 0; qi < 4; qi++) {
    #pragma unroll
    for (int r = 0; r < 4; r++) {
      int i = qi*16 + g*4 + r;
      int s1i = i >> 3, s2i = i & 7;
      int zi = zone1(s1i*8 + i2)*3 + zone1(s2i*8 + j2);
      #pragma unroll
      for (int kj = 0; kj < 4; kj++) {
        int j = kj*16 + rr;
        int s1j = j >> 3, s2j = j & 7;
        float bv = rpb[((s1i - s1j + 7)*15 + (s2i - s2j + 7))*16 + head];
        int zj = zone1(s1j*8 + i2)*3 + zone1(s2j*8 + j2);
        s[qi][kj][r] += bv + (zi != zj ? -1e10f : 0.f);
      }
    }
  }

  float inv[4][4];
  #pragma unroll
  for (int qi = 0; qi < 4; qi++) {
    #pragma unroll
    for (int r = 0; r < 4; r++) {
      float mx = fmaxf(fmaxf(s[qi][0][r], s[qi][1][r]), fmaxf(s[qi][2][r], s[qi][3][r]));
      mx = fmaxf(mx, __shfl_xor(mx, 1));
      mx = fmaxf(mx, __shfl_xor(mx, 2));
      mx = fmaxf(mx, __shfl_xor(mx, 4));
      mx = fmaxf(mx, __shfl_xor(mx, 8));
      float sum = 0.f;
      #pragma unroll
      for (int kj = 0; kj < 4; kj++) {
        float e = __expf(s[qi][kj][r] - mx);
        s[qi][kj][r] = e;
        sum += e;
      }
      sum += __shfl_xor(sum, 1);
      sum += __shfl_xor(sum, 2);
      sum += __shfl_xor(sum, 4);
      sum += __shfl_xor(sum, 8);
      inv[qi][r] = 1.f / sum;
    }
  }

  #pragma unroll
  for (int qi = 0; qi < 4; qi++)
    #pragma unroll
    for (int kj = 0; kj < 4; kj++)
      #pragma unroll
      for (int r = 0; r < 4; r++)
        P[wid][qi*16 + g*4 + r][kj*16 + rr] = f2bf(s[qi][kj][r]);

  f32x4 o[4][2] = {};
  #pragma unroll
  for (int jh = 0; jh < 2; jh++) {
    short8 vf[2];
    #pragma unroll
    for (int df = 0; df < 2; df++)
      vf[df] = *(const short8*)(vv + (size_t)(df*16 + rr)*64 + jh*32 + g*8);
    #pragma unroll
    for (int qi = 0; qi < 4; qi++) {
      short8 pf = *(const short8*)(&P[wid][qi*16 + rr][jh*32 + g*8]);
      #pragma unroll
      for (int df = 0; df < 2; df++)
        o[qi][df] = __builtin_amdgcn_mfma_f32_16x16x32_bf16(pf, vf[df], o[qi][df], 0, 0, 0);
    }
  }

  #pragma unroll
  for (int qi = 0; qi < 4; qi++)
    #pragma unroll
    for (int df = 0; df < 2; df++)
      #pragma unroll
      for (int r = 0; r < 4; r++) {
        int t = qi*16 + g*4 + r;
        int d = df*16 + rr;
        outb[(size_t)(w*64 + t)*512 + head*32 + d] = f2bf(o[qi][df][r] * inv[qi][r]);
      }
}

extern "C" void kernel_launch(void* const* d_in, const int* in_sizes, int n_in,
                              void* d_out, int out_size, void* d_ws, size_t ws_size,
                              hipStream_t stream) {
  const float* x     = (const float*)d_in[0];
  const float* ln1w  = (const float*)d_in[1];
  const float* ln1b  = (const float*)d_in[2];
  const float* qkvw  = (const float*)d_in[3];
  const float* qkvb  = (const float*)d_in[4];
  const float* rpb   = (const float*)d_in[5];
  const float* projw = (const float*)d_in[6];
  const float* projb = (const float*)d_in[7];
  const float* ln2w  = (const float*)d_in[8];
  const float* ln2b  = (const float*)d_in[9];
  const float* fc1w  = (const float*)d_in[10];
  const float* fc1b  = (const float*)d_in[11];
  const float* fc2w  = (const float*)d_in[12];
  const float* fc2b  = (const float*)d_in[13];
  float* out = (float*)d_out;

  char* ws = (char*)d_ws;
  u16* wqkv  = (u16*)(ws + 0);         // 786432 el (permuted cols)
  u16* wproj = (u16*)(ws + 1572864);   // 262144 el
  u16* wfc1  = (u16*)(ws + 2097152);   // 1048576 el
  u16* wfc2  = (u16*)(ws + 4194304);   // 1048576 el
  float* pb  = (float*)(ws + 6291456); // 1536 el (permuted qkv bias)
  size_t base = 8ull << 20;
  u16* xw = (u16*)(ws + base);                      // 64 MiB  (aliased later: attn, z)
  u16* qb = (u16*)(ws + base + (64ull  << 20));     // 64 MiB  (aliased later: part of h)
  u16* kb = (u16*)(ws + base + (128ull << 20));     // 64 MiB
  u16* vb = (u16*)(ws + base + (192ull << 20));     // 64 MiB
  u16* attnb = xw;
  u16* zb    = xw;
  u16* hb    = qb;                                  // 256 MiB -> ws end 328 MiB

  // weights -> bf16 (qkv permuted)
  cvt_qkvw<<<768, 256, 0, stream>>>((const float4*)qkvw, (us4*)wqkv);
  perm_qkvb<<<6, 256, 0, stream>>>(qkvb, pb);
  cvt_bf16<<<256,  256, 0, stream>>>((const float4*)projw, (us4*)wproj, 65536);
  cvt_bf16<<<1024, 256, 0, stream>>>((const float4*)fc1w,  (us4*)wfc1,  262144);
  cvt_bf16<<<1024, 256, 0, stream>>>((const float4*)fc2w,  (us4*)wfc2,  262144);

  // LN1 + roll + window partition
  ln_kernel<true><<<16384, 256, 0, stream>>>(x, ln1w, ln1b, xw);
  // QKV: grid (65536/256) x (1536/256) = 1536
  gemm_k<0><<<1536, 512, 0, stream>>>(xw, wqkv, pb, qb, kb, vb, nullptr, nullptr,
                                      65536, 1536, 512);
  // attention
  attn_k<<<4096, 256, 0, stream>>>(qb, kb, vb, rpb, attnb);
  // proj + win_reverse + residual -> d_out (= x2): 256 x 2 = 512
  gemm_k<1><<<512, 512, 0, stream>>>(attnb, wproj, projb, nullptr, nullptr, nullptr,
                                     out, x, 65536, 512, 512);
  // LN2
  ln_kernel<false><<<16384, 256, 0, stream>>>(out, ln2w, ln2b, zb);
  // fc1 + gelu: 256 x 8 = 2048
  gemm_k<2><<<2048, 512, 0, stream>>>(zb, wfc1, fc1b, hb, nullptr, nullptr, nullptr, nullptr,
                                      65536, 2048, 512);
  // fc2 + residual (in-place on d_out): 256 x 2 = 512
  gemm_k<3><<<512, 512, 0, stream>>>(hb, wfc2, fc2b, nullptr, nullptr, nullptr, out, nullptr,
                                     65536, 512, 2048);
}